// Round 1
// baseline (1786.956 us; speedup 1.0000x reference)
//
#include <hip/hip_runtime.h>

#define NN 10000
#define NE 160000
#define TT 2
#define SS 2
#define HH 64
#define ZZ 32
#define KK 4
#define NIN 4

// ---- monotonic float<->uint encoding for atomicMax on floats ----
__device__ __forceinline__ unsigned enc_f(float f) {
    unsigned u = __float_as_uint(f);
    return (u & 0x80000000u) ? ~u : (u | 0x80000000u);
}
__device__ __forceinline__ float dec_f(unsigned u) {
    return __uint_as_float((u & 0x80000000u) ? (u ^ 0x80000000u) : ~u);
}

// A0: M[k][i][j] = sum_h Ws[k,h,i] * Wd[k,h,j]   (grid 128 = K*Z, block 32)
__global__ void k_attnM(const float* __restrict__ Ws, const float* __restrict__ Wd,
                        float* __restrict__ M) {
    int k = blockIdx.x >> 5;
    int i = blockIdx.x & 31;
    int j = threadIdx.x;
    float acc = 0.0f;
    for (int h = 0; h < HH; ++h)
        acc += Ws[(k*HH + h)*ZZ + i] * Wd[(k*HH + h)*ZZ + j];
    M[(k*ZZ + i)*ZZ + j] = acc;
}

// A1: q[n,s,k,j] = sum_i zG[n,s,i] * M[k][i][j]
__global__ void k_q(const float* __restrict__ zG, const float* __restrict__ M,
                    float* __restrict__ q) {
    int t = blockIdx.x * blockDim.x + threadIdx.x;
    if (t >= NN*SS*KK*ZZ) return;
    int j  = t & 31;
    int k  = (t >> 5) & 3;
    int ns = t >> 7;
    const float* zg = zG + ns*ZZ;
    const float* m  = M + k*ZZ*ZZ;
    float acc = 0.0f;
#pragma unroll
    for (int i = 0; i < ZZ; ++i) acc += zg[i] * m[i*ZZ + j];
    q[t] = acc;
}

// A2: e[e,s,k] = leaky(dot(q[src,s,k,:], zG[dst,s,:])); atomicMax per (dst,s,k); deg count
__global__ void k_edge_e(const float* __restrict__ q, const float* __restrict__ zG,
                         const int* __restrict__ src, const int* __restrict__ dst,
                         float* __restrict__ e_arr, unsigned* __restrict__ mbuf,
                         int* __restrict__ deg_i) {
    int t = blockIdx.x * blockDim.x + threadIdx.x;
    if (t >= NE*SS*KK) return;
    int k = t & 3;
    int s = (t >> 2) & 1;
    int e = t >> 3;
    int sn = src[e], dn = dst[e];
    const float* qq = q  + ((sn*SS + s)*KK + k)*ZZ;
    const float* zg = zG + (dn*SS + s)*ZZ;
    float acc = 0.0f;
#pragma unroll
    for (int j = 0; j < ZZ; ++j) acc += qq[j] * zg[j];
    float ev = acc > 0.0f ? acc : 0.01f*acc;
    e_arr[t] = ev;
    atomicMax(mbuf + (dn*SS + s)*KK + k, enc_f(ev));
    if ((t & 7) == 0) atomicAdd(deg_i + dn, 1);
}

// A3: ex = exp(e - m[dst]); denom += ex  (e_arr overwritten with ex)
__global__ void k_edge_softmax(const int* __restrict__ dst, float* __restrict__ e_arr,
                               const unsigned* __restrict__ mbuf, float* __restrict__ denom) {
    int t = blockIdx.x * blockDim.x + threadIdx.x;
    if (t >= NE*SS*KK) return;
    int k = t & 3;
    int s = (t >> 2) & 1;
    int e = t >> 3;
    int dn = dst[e];
    float m = dec_f(mbuf[(dn*SS + s)*KK + k]);
    float ex = __expf(e_arr[t] - m);
    e_arr[t] = ex;
    atomicAdd(denom + (dn*SS + s)*KK + k, ex);
}

// C2: exclusive scan of deg_i -> offsets[0..NN], cursor copy (single block, 1024 thr)
__global__ void k_scan(const int* __restrict__ deg_i, int* __restrict__ offsets,
                       int* __restrict__ cursor) {
    __shared__ int part[1024];
    int tidx = threadIdx.x;
    const int CH = (NN + 1023) / 1024;   // 10
    int b0 = tidx * CH;
    int sum = 0;
    for (int i = 0; i < CH; ++i) { int idx = b0 + i; if (idx < NN) sum += deg_i[idx]; }
    part[tidx] = sum;
    __syncthreads();
    if (tidx == 0) {
        int run = 0;
        for (int i = 0; i < 1024; ++i) { int tmp = part[i]; part[i] = run; run += tmp; }
    }
    __syncthreads();
    int run = part[tidx];
    for (int i = 0; i < CH; ++i) {
        int idx = b0 + i;
        if (idx < NN) { offsets[idx] = run; cursor[idx] = run; run += deg_i[idx]; }
    }
    if (tidx == 0) offsets[NN] = NE;
}

// C3: scatter edge ids into dst-sorted order
__global__ void k_scatter(const int* __restrict__ dst, int* __restrict__ cursor,
                          int* __restrict__ edge_by_dst) {
    int e = blockIdx.x * blockDim.x + threadIdx.x;
    if (e >= NE) return;
    int pos = atomicAdd(cursor + dst[e], 1);
    edge_by_dst[pos] = e;
}

// B0: xt[n,s,i] = inputs[n, 0, i]
__global__ void k_xt0(const float* __restrict__ inputs, float* __restrict__ xt) {
    int t = blockIdx.x * blockDim.x + threadIdx.x;
    if (t >= NN*SS*NIN) return;
    int i = t & 3;
    int n = t >> 3;
    xt[t] = inputs[n*(TT*NIN) + i];
}

// B1: xt_enc[n,s,h] = b[h] + sum_i xt[n,s,i]*w[h,i]
__global__ void k_xenc(const float* __restrict__ xt, const float* __restrict__ w,
                       const float* __restrict__ b, float* __restrict__ xt_enc) {
    int t = blockIdx.x * blockDim.x + threadIdx.x;
    if (t >= NN*SS*HH) return;
    int h  = t & 63;
    int ns = t >> 6;
    const float* x = xt + ns*NIN;
    float acc = b[h];
#pragma unroll
    for (int i = 0; i < NIN; ++i) acc += x[i] * w[h*NIN + i];
    xt_enc[t] = acc;
}

// B2: fused edge MLP + attention-weighted aggregation over CSR.
// block=256 (4 waves), one (n,s) item at a time, 4 edges per lockstep iteration.
__global__ __launch_bounds__(256) void k_edge_mlp_agg(
    const float* __restrict__ xt_enc, const float* __restrict__ F2w1,
    const float* __restrict__ F2w2, const int* __restrict__ offsets,
    const int* __restrict__ edge_by_dst, const int* __restrict__ src,
    const float* __restrict__ exv, const float* __restrict__ denom,
    float* __restrict__ res)
{
    __shared__ float w1s[128*64];   // w1s[j*64+h] = F2w1[h*128+j] (transposed, conflict-free reads)
    __shared__ float w2s[64*64];    // w2s[j*64+h] = F2w2[h*64+j]
    __shared__ float dcat[64];
    __shared__ float scat[4][64];
    __shared__ float hid[4][64];
    __shared__ float aw[4][4];
    __shared__ float dinvk[4];
    __shared__ float rsum[256];
    int tid = threadIdx.x;
    int w = tid >> 6, h = tid & 63;
    for (int idx = tid; idx < 64*128; idx += 256) {
        int hh = idx >> 7, j = idx & 127;
        w1s[j*64 + hh] = F2w1[idx];
    }
    for (int idx = tid; idx < 64*64; idx += 256) {
        int hh = idx >> 6, j = idx & 63;
        w2s[j*64 + hh] = F2w2[idx];
    }
    __syncthreads();
    for (int item = blockIdx.x; item < NN*SS; item += gridDim.x) {
        int n = item >> 1, s = item & 1;
        int r0 = offsets[n], r1 = offsets[n+1];
        if (tid < 64) dcat[tid] = xt_enc[item*HH + tid];
        if (tid < 4)  dinvk[tid] = 1.0f / denom[item*KK + tid];
        rsum[tid] = 0.0f;
        float acc0 = 0.0f, acc1 = 0.0f, acc2 = 0.0f, acc3 = 0.0f;
        __syncthreads();
        for (int base = r0; base < r1; base += 4) {
            int idx = base + w;
            bool valid = idx < r1;
            if (valid) {
                int e = edge_by_dst[idx];
                int sn = src[e];
                scat[w][h] = xt_enc[(sn*SS + s)*HH + h];
                if (h < 4) aw[w][h] = exv[(e*SS + s)*KK + h] * dinvk[h];
            }
            __syncthreads();
            if (valid) {
                float hv = 0.0f;
                const float* c = scat[w];
#pragma unroll
                for (int j = 0; j < 64; ++j) hv += w1s[j*64 + h] * c[j];
#pragma unroll
                for (int j = 0; j < 64; ++j) hv += w1s[(64 + j)*64 + h] * dcat[j];
                hid[w][h] = hv > 0.0f ? hv : 0.0f;
            }
            __syncthreads();
            if (valid) {
                float d = 0.0f;
#pragma unroll
                for (int j = 0; j < 64; ++j) d += w2s[j*64 + h] * hid[w][j];
                acc0 += aw[w][0]*d;
                acc1 += aw[w][1]*d;
                acc2 += aw[w][2]*d;
                acc3 += aw[w][3]*d;
            }
            __syncthreads();
        }
        atomicAdd(&rsum[h],        acc0);
        atomicAdd(&rsum[64 + h],   acc1);
        atomicAdd(&rsum[128 + h],  acc2);
        atomicAdd(&rsum[192 + h],  acc3);
        __syncthreads();
        int degv = r1 - r0;
        float dinvdeg = 1.0f / (float)(degv > 1 ? degv : 1);
        res[item*256 + tid] = rsum[tid] * dinvdeg;
        __syncthreads();
    }
}

// B3: per-(n,s) node update: F1 MLP -> concat zA -> out MLP -> xt += dx, write preds
__global__ __launch_bounds__(64) void k_node_update(
    const float* __restrict__ res, const float* __restrict__ zA,
    const float* __restrict__ F1w1, const float* __restrict__ F1w2,
    const float* __restrict__ ow1, const float* __restrict__ ob1,
    const float* __restrict__ ow2, const float* __restrict__ ob2,
    float* __restrict__ xt, float* __restrict__ out, int tstep)
{
    __shared__ float rs[256];
    __shared__ float hid1[64];
    __shared__ float hcat[96];
    __shared__ float hid2[64];
    int item = blockIdx.x;
    int h = threadIdx.x;
    ((float4*)rs)[h] = ((const float4*)(res + item*256))[h];
    __syncthreads();
    {
        const float4* w14 = (const float4*)(F1w1 + h*256);
        const float4* rs4 = (const float4*)rs;
        float a = 0.0f;
#pragma unroll
        for (int j = 0; j < 64; ++j) {
            float4 wv = w14[j]; float4 rv = rs4[j];
            a += wv.x*rv.x + wv.y*rv.y + wv.z*rv.z + wv.w*rv.w;
        }
        hid1[h] = a > 0.0f ? a : 0.0f;
    }
    __syncthreads();
    {
        const float4* w24 = (const float4*)(F1w2 + h*64);
        const float4* h14 = (const float4*)hid1;
        float d = 0.0f;
#pragma unroll
        for (int j = 0; j < 16; ++j) {
            float4 wv = w24[j]; float4 hv = h14[j];
            d += wv.x*hv.x + wv.y*hv.y + wv.z*hv.z + wv.w*hv.w;
        }
        hcat[h] = d;                      // deltax (no relu)
        if (h < 32) hcat[64 + h] = zA[item*ZZ + h];
    }
    __syncthreads();
    {
        const float4* o14 = (const float4*)(ow1 + h*96);
        const float4* hc4 = (const float4*)hcat;
        float a2 = ob1[h];
#pragma unroll
        for (int j = 0; j < 24; ++j) {
            float4 wv = o14[j]; float4 hv = hc4[j];
            a2 += wv.x*hv.x + wv.y*hv.y + wv.z*hv.z + wv.w*hv.w;
        }
        hid2[h] = a2 > 0.0f ? a2 : 0.0f;
    }
    __syncthreads();
    if (h < 4) {
        const float4* o24 = (const float4*)(ow2 + h*64);
        const float4* h24 = (const float4*)hid2;
        float dx = ob2[h];
#pragma unroll
        for (int j = 0; j < 16; ++j) {
            float4 wv = o24[j]; float4 hv = h24[j];
            dx += wv.x*hv.x + wv.y*hv.y + wv.z*hv.z + wv.w*hv.w;
        }
        int n = item >> 1, s = item & 1;
        float nx = xt[item*4 + h] + dx;
        xt[item*4 + h] = nx;
        out[((n*TT + tstep)*SS + s)*4 + h] = nx;
    }
}

extern "C" void kernel_launch(void* const* d_in, const int* in_sizes, int n_in,
                              void* d_out, int out_size, void* d_ws, size_t ws_size,
                              hipStream_t stream) {
    const float* inputs = (const float*)d_in[0];
    const float* zA     = (const float*)d_in[1];
    const float* zG     = (const float*)d_in[2];
    const int*   src    = (const int*)d_in[3];
    const int*   dst    = (const int*)d_in[4];
    const float* Ws     = (const float*)d_in[5];
    const float* Wd     = (const float*)d_in[6];
    const float* F2w1   = (const float*)d_in[7];
    const float* F2w2   = (const float*)d_in[8];
    const float* F1w1   = (const float*)d_in[9];
    const float* F1w2   = (const float*)d_in[10];
    const float* xw     = (const float*)d_in[11];
    const float* xb     = (const float*)d_in[12];
    const float* ow1    = (const float*)d_in[13];
    const float* ob1    = (const float*)d_in[14];
    const float* ow2    = (const float*)d_in[15];
    const float* ob2    = (const float*)d_in[16];
    float* out = (float*)d_out;

    // ---- workspace carve (floats/ints, all 4B) ----
    float*    M           = (float*)d_ws;                       // 4096
    float*    q           = M + 4096;                           // 2,560,000
    float*    e_arr       = q + 2560000;                        // 1,280,000
    unsigned* mbuf        = (unsigned*)(e_arr + 1280000);       // 80,000  (zeroed)
    float*    denom       = (float*)(mbuf + 80000);             // 80,000  (zeroed)
    int*      deg_i       = (int*)(denom + 80000);              // 10,000  (zeroed)
    int*      offsets     = deg_i + 10000;                      // 10,001
    int*      cursor      = offsets + 10001;                    // 10,000
    int*      edge_by_dst = cursor + 10000;                     // 160,000
    float*    xt          = (float*)(edge_by_dst + 160000);     // 80,000
    float*    xt_enc      = xt + 80000;                         // 1,280,000
    float*    res         = xt_enc + 1280000;                   // 5,120,000

    // zero mbuf+denom+deg_i in one shot (contiguous: 170,000 * 4B)
    hipMemsetAsync(mbuf, 0, 170000u * 4u, stream);

    // ---- attention phase (once) ----
    k_attnM<<<KK*ZZ, ZZ, 0, stream>>>(Ws, Wd, M);
    k_q<<<(NN*SS*KK*ZZ + 255)/256, 256, 0, stream>>>(zG, M, q);
    k_edge_e<<<(NE*SS*KK + 255)/256, 256, 0, stream>>>(q, zG, src, dst, e_arr, mbuf, deg_i);
    k_edge_softmax<<<(NE*SS*KK + 255)/256, 256, 0, stream>>>(dst, e_arr, mbuf, denom);
    k_scan<<<1, 1024, 0, stream>>>(deg_i, offsets, cursor);
    k_scatter<<<(NE + 255)/256, 256, 0, stream>>>(dst, cursor, edge_by_dst);

    // ---- time stepping ----
    k_xt0<<<(NN*SS*NIN + 255)/256, 256, 0, stream>>>(inputs, xt);
    for (int t = 0; t < 2; ++t) {
        k_xenc<<<(NN*SS*HH + 255)/256, 256, 0, stream>>>(xt, xw, xb, xt_enc);
        k_edge_mlp_agg<<<768, 256, 0, stream>>>(xt_enc, F2w1, F2w2, offsets,
                                                edge_by_dst, src, e_arr, denom, res);
        k_node_update<<<NN*SS, 64, 0, stream>>>(res, zA, F1w1, F1w2,
                                                ow1, ob1, ow2, ob2, xt, out, t);
    }
}

// Round 2
// 881.715 us; speedup vs baseline: 2.0267x; 2.0267x over previous
//
#include <hip/hip_runtime.h>

#define NN 10000
#define NE 160000
#define TT 2
#define SS 2
#define HH 64
#define ZZ 32
#define KK 4
#define NIN 4

typedef short bf16x8 __attribute__((ext_vector_type(8)));
typedef float f32x4 __attribute__((ext_vector_type(4)));

// ---- monotonic float<->uint encoding for atomicMax on floats ----
__device__ __forceinline__ unsigned enc_f(float f) {
    unsigned u = __float_as_uint(f);
    return (u & 0x80000000u) ? ~u : (u | 0x80000000u);
}
__device__ __forceinline__ float dec_f(unsigned u) {
    return __uint_as_float((u & 0x80000000u) ? (u ^ 0x80000000u) : ~u);
}
// fp32 -> bf16 (RNE)
__device__ __forceinline__ unsigned short f2b(float x) {
    unsigned u = __float_as_uint(x);
    u += 0x7fffu + ((u >> 16) & 1u);
    return (unsigned short)(u >> 16);
}

// A0: M[k][i][j] = sum_h Ws[k,h,i] * Wd[k,h,j]   (grid 128 = K*Z, block 32)
__global__ void k_attnM(const float* __restrict__ Ws, const float* __restrict__ Wd,
                        float* __restrict__ M) {
    int k = blockIdx.x >> 5;
    int i = blockIdx.x & 31;
    int j = threadIdx.x;
    float acc = 0.0f;
    for (int h = 0; h < HH; ++h)
        acc += Ws[(k*HH + h)*ZZ + i] * Wd[(k*HH + h)*ZZ + j];
    M[(k*ZZ + i)*ZZ + j] = acc;
}

// A1: q[n,s,k,j] = sum_i zG[n,s,i] * M[k][i][j]
__global__ void k_q(const float* __restrict__ zG, const float* __restrict__ M,
                    float* __restrict__ q) {
    int t = blockIdx.x * blockDim.x + threadIdx.x;
    if (t >= NN*SS*KK*ZZ) return;
    int j  = t & 31;
    int k  = (t >> 5) & 3;
    int ns = t >> 7;
    const float* zg = zG + ns*ZZ;
    const float* m  = M + k*ZZ*ZZ;
    float acc = 0.0f;
#pragma unroll
    for (int i = 0; i < ZZ; ++i) acc += zg[i] * m[i*ZZ + j];
    q[t] = acc;
}

// A2: e[e,s,k] = leaky(dot(q[src,s,k,:], zG[dst,s,:])); atomicMax per (dst,s,k); deg count
__global__ void k_edge_e(const float* __restrict__ q, const float* __restrict__ zG,
                         const int* __restrict__ src, const int* __restrict__ dst,
                         float* __restrict__ e_arr, unsigned* __restrict__ mbuf,
                         int* __restrict__ deg_i) {
    int t = blockIdx.x * blockDim.x + threadIdx.x;
    if (t >= NE*SS*KK) return;
    int k = t & 3;
    int s = (t >> 2) & 1;
    int e = t >> 3;
    int sn = src[e], dn = dst[e];
    const float* qq = q  + ((sn*SS + s)*KK + k)*ZZ;
    const float* zg = zG + (dn*SS + s)*ZZ;
    float acc = 0.0f;
#pragma unroll
    for (int j = 0; j < ZZ; ++j) acc += qq[j] * zg[j];
    float ev = acc > 0.0f ? acc : 0.01f*acc;
    e_arr[t] = ev;
    atomicMax(mbuf + (dn*SS + s)*KK + k, enc_f(ev));
    if ((t & 7) == 0) atomicAdd(deg_i + dn, 1);
}

// A3: ex = exp(e - m[dst]); denom += ex  (e_arr overwritten with ex)
__global__ void k_edge_softmax(const int* __restrict__ dst, float* __restrict__ e_arr,
                               const unsigned* __restrict__ mbuf, float* __restrict__ denom) {
    int t = blockIdx.x * blockDim.x + threadIdx.x;
    if (t >= NE*SS*KK) return;
    int k = t & 3;
    int s = (t >> 2) & 1;
    int e = t >> 3;
    int dn = dst[e];
    float m = dec_f(mbuf[(dn*SS + s)*KK + k]);
    float ex = __expf(e_arr[t] - m);
    e_arr[t] = ex;
    atomicAdd(denom + (dn*SS + s)*KK + k, ex);
}

// C2: exclusive scan of deg_i -> offsets[0..NN], cursor copy (single block, 1024 thr)
__global__ void k_scan(const int* __restrict__ deg_i, int* __restrict__ offsets,
                       int* __restrict__ cursor) {
    __shared__ int part[1024];
    int tidx = threadIdx.x;
    const int CH = (NN + 1023) / 1024;   // 10
    int b0 = tidx * CH;
    int sum = 0;
    for (int i = 0; i < CH; ++i) { int idx = b0 + i; if (idx < NN) sum += deg_i[idx]; }
    part[tidx] = sum;
    __syncthreads();
    if (tidx == 0) {
        int run = 0;
        for (int i = 0; i < 1024; ++i) { int tmp = part[i]; part[i] = run; run += tmp; }
    }
    __syncthreads();
    int run = part[tidx];
    for (int i = 0; i < CH; ++i) {
        int idx = b0 + i;
        if (idx < NN) { offsets[idx] = run; cursor[idx] = run; run += deg_i[idx]; }
    }
    if (tidx == 0) offsets[NN] = NE;
}

// C3: scatter edge ids into dst-sorted order
__global__ void k_scatter(const int* __restrict__ dst, int* __restrict__ cursor,
                          int* __restrict__ edge_by_dst) {
    int e = blockIdx.x * blockDim.x + threadIdx.x;
    if (e >= NE) return;
    int pos = atomicAdd(cursor + dst[e], 1);
    edge_by_dst[pos] = e;
}

// W0: convert F2 weights to bf16
__global__ void k_wconv(const float* __restrict__ F2w1, const float* __restrict__ F2w2,
                        unsigned short* __restrict__ W1b, unsigned short* __restrict__ W2b) {
    int t = blockIdx.x * blockDim.x + threadIdx.x;
    if (t < HH*2*HH) W1b[t] = f2b(F2w1[t]);
    if (t < HH*HH)   W2b[t] = f2b(F2w2[t]);
}

// B0: xt[n,s,i] = inputs[n, 0, i]
__global__ void k_xt0(const float* __restrict__ inputs, float* __restrict__ xt) {
    int t = blockIdx.x * blockDim.x + threadIdx.x;
    if (t >= NN*SS*NIN) return;
    int i = t & 3;
    int n = t >> 3;
    xt[t] = inputs[n*(TT*NIN) + i];
}

// B1: xt_enc (bf16) = xt @ xenc_w.T + b
__global__ void k_xenc(const float* __restrict__ xt, const float* __restrict__ w,
                       const float* __restrict__ b, unsigned short* __restrict__ xtb) {
    int t = blockIdx.x * blockDim.x + threadIdx.x;
    if (t >= NN*SS*HH) return;
    int h  = t & 63;
    int ns = t >> 6;
    const float* x = xt + ns*NIN;
    float acc = b[h];
#pragma unroll
    for (int i = 0; i < NIN; ++i) acc += x[i] * w[h*NIN + i];
    xtb[t] = f2b(acc);
}

// B2: edge MLP as bf16 MFMA GEMM over dst-sorted edge-sample rows.
// 5000 blocks x 256 threads; each block: 64 rows (32 sorted edges x 2 samples).
// dA output row m = idx*2 + s  (idx = position in edge_by_dst), stored bf16.
__global__ __launch_bounds__(256) void k_edge_mfma(
    const unsigned short* __restrict__ xtb, const unsigned short* __restrict__ W1b,
    const unsigned short* __restrict__ W2b, const int* __restrict__ edge_by_dst,
    const int* __restrict__ src, const int* __restrict__ dst,
    unsigned short* __restrict__ dA)
{
    __shared__ unsigned short cat_s[64*136];   // row stride 136 (272B): 2-way max aliasing
    __shared__ unsigned short hid_s[4*16*72];  // per-wave 16x64 hidden, stride 72
    int tid = threadIdx.x;
    int w   = tid >> 6;
    int l   = tid & 63;
    int l15 = l & 15;
    int qq  = l >> 4;

    // weight B-fragments in registers: B[k][n] = W[n][k]; lane n = l15, k = kb*32+qq*8+j
    bf16x8 b1[4][4], b2[2][4];
#pragma unroll
    for (int nb = 0; nb < 4; ++nb) {
        int n = nb*16 + l15;
#pragma unroll
        for (int kb = 0; kb < 4; ++kb)
            b1[kb][nb] = *(const bf16x8*)(W1b + n*128 + kb*32 + qq*8);
#pragma unroll
        for (int kb = 0; kb < 2; ++kb)
            b2[kb][nb] = *(const bf16x8*)(W2b + n*64 + kb*32 + qq*8);
    }

    int tile = blockIdx.x;
    // ---- stage cat tile: 4 threads per row, 32 bf16 (64B) each ----
    {
        int r = tid >> 2, qc = tid & 3;
        int m = tile*64 + r;
        int idx = m >> 1, s = m & 1;
        int e = edge_by_dst[idx];
        int node = (qc < 2) ? src[e] : dst[e];
        const unsigned short* sp = xtb + (node*SS + s)*HH + (qc & 1)*32;
        unsigned short* dp = cat_s + r*136 + qc*32;
        *(uint4*)(dp)      = *(const uint4*)(sp);
        *(uint4*)(dp + 8)  = *(const uint4*)(sp + 8);
        *(uint4*)(dp + 16) = *(const uint4*)(sp + 16);
        *(uint4*)(dp + 24) = *(const uint4*)(sp + 24);
    }
    __syncthreads();

    // ---- GEMM1: [16x128] @ [128x64] per wave ----
    f32x4 acc[4];
#pragma unroll
    for (int nb = 0; nb < 4; ++nb) acc[nb] = (f32x4)(0.0f);
    const unsigned short* arow = cat_s + (w*16 + l15)*136 + qq*8;
#pragma unroll
    for (int kb = 0; kb < 4; ++kb) {
        bf16x8 af = *(const bf16x8*)(arow + kb*32);
#pragma unroll
        for (int nb = 0; nb < 4; ++nb)
            acc[nb] = __builtin_amdgcn_mfma_f32_16x16x32_bf16(af, b1[kb][nb], acc[nb], 0, 0, 0);
    }

    // relu + stage hidden (per-wave LDS region; no block barrier needed)
    unsigned short* hw = hid_s + w*16*72;
#pragma unroll
    for (int nb = 0; nb < 4; ++nb)
#pragma unroll
        for (int r = 0; r < 4; ++r) {
            float v = acc[nb][r];
            hw[(qq*4 + r)*72 + nb*16 + l15] = f2b(v > 0.0f ? v : 0.0f);
        }

    // ---- GEMM2: [16x64] @ [64x64] per wave ----
    f32x4 acc2[4];
#pragma unroll
    for (int nb = 0; nb < 4; ++nb) acc2[nb] = (f32x4)(0.0f);
    const unsigned short* a2row = hid_s + w*16*72 + l15*72 + qq*8;
#pragma unroll
    for (int kb = 0; kb < 2; ++kb) {
        bf16x8 af = *(const bf16x8*)(a2row + kb*32);
#pragma unroll
        for (int nb = 0; nb < 4; ++nb)
            acc2[nb] = __builtin_amdgcn_mfma_f32_16x16x32_bf16(af, b2[kb][nb], acc2[nb], 0, 0, 0);
    }

    // ---- write dA (bf16) ----
    unsigned short* drow = dA + (tile*64 + w*16)*64;
#pragma unroll
    for (int nb = 0; nb < 4; ++nb)
#pragma unroll
        for (int r = 0; r < 4; ++r)
            drow[(qq*4 + r)*64 + nb*16 + l15] = f2b(acc2[nb][r]);
}

// B2b: attention-weighted aggregation per (n,s): res[item, k*64+h]
__global__ __launch_bounds__(64) void k_agg(
    const unsigned short* __restrict__ dA, const int* __restrict__ edge_by_dst,
    const int* __restrict__ offsets, const float* __restrict__ exv,
    const float* __restrict__ denom, float* __restrict__ res)
{
    int item = blockIdx.x;
    int n = item >> 1, s = item & 1;
    int h = threadIdx.x;
    int r0 = offsets[n], r1 = offsets[n+1];
    float a0 = 0.f, a1 = 0.f, a2 = 0.f, a3 = 0.f;
    for (int idx = r0; idx < r1; ++idx) {
        int e = edge_by_dst[idx];
        const float4 al = *(const float4*)(exv + (e*SS + s)*KK);
        unsigned short uv = dA[(idx*2 + s)*64 + h];
        float v = __uint_as_float(((unsigned)uv) << 16);
        a0 += al.x*v; a1 += al.y*v; a2 += al.z*v; a3 += al.w*v;
    }
    int degv = r1 - r0;
    float dinvdeg = 1.0f / (float)(degv > 1 ? degv : 1);
    const float4 dn4 = *(const float4*)(denom + item*KK);
    float i0 = dn4.x != 0.f ? 1.f/dn4.x : 0.f;
    float i1 = dn4.y != 0.f ? 1.f/dn4.y : 0.f;
    float i2 = dn4.z != 0.f ? 1.f/dn4.z : 0.f;
    float i3 = dn4.w != 0.f ? 1.f/dn4.w : 0.f;
    res[item*256 +       h] = a0 * dinvdeg * i0;
    res[item*256 + 64  + h] = a1 * dinvdeg * i1;
    res[item*256 + 128 + h] = a2 * dinvdeg * i2;
    res[item*256 + 192 + h] = a3 * dinvdeg * i3;
}

// B3: per-(n,s) node update: F1 MLP -> concat zA -> out MLP -> xt += dx, write preds
__global__ __launch_bounds__(64) void k_node_update(
    const float* __restrict__ res, const float* __restrict__ zA,
    const float* __restrict__ F1w1, const float* __restrict__ F1w2,
    const float* __restrict__ ow1, const float* __restrict__ ob1,
    const float* __restrict__ ow2, const float* __restrict__ ob2,
    float* __restrict__ xt, float* __restrict__ out, int tstep)
{
    __shared__ float rs[256];
    __shared__ float hid1[64];
    __shared__ float hcat[96];
    __shared__ float hid2[64];
    int item = blockIdx.x;
    int h = threadIdx.x;
    ((float4*)rs)[h] = ((const float4*)(res + item*256))[h];
    __syncthreads();
    {
        const float4* w14 = (const float4*)(F1w1 + h*256);
        const float4* rs4 = (const float4*)rs;
        float a = 0.0f;
#pragma unroll
        for (int j = 0; j < 64; ++j) {
            float4 wv = w14[j]; float4 rv = rs4[j];
            a += wv.x*rv.x + wv.y*rv.y + wv.z*rv.z + wv.w*rv.w;
        }
        hid1[h] = a > 0.0f ? a : 0.0f;
    }
    __syncthreads();
    {
        const float4* w24 = (const float4*)(F1w2 + h*64);
        const float4* h14 = (const float4*)hid1;
        float d = 0.0f;
#pragma unroll
        for (int j = 0; j < 16; ++j) {
            float4 wv = w24[j]; float4 hv = h14[j];
            d += wv.x*hv.x + wv.y*hv.y + wv.z*hv.z + wv.w*hv.w;
        }
        hcat[h] = d;                      // deltax (no relu)
        if (h < 32) hcat[64 + h] = zA[item*ZZ + h];
    }
    __syncthreads();
    {
        const float4* o14 = (const float4*)(ow1 + h*96);
        const float4* hc4 = (const float4*)hcat;
        float a2 = ob1[h];
#pragma unroll
        for (int j = 0; j < 24; ++j) {
            float4 wv = o14[j]; float4 hv = hc4[j];
            a2 += wv.x*hv.x + wv.y*hv.y + wv.z*hv.z + wv.w*hv.w;
        }
        hid2[h] = a2 > 0.0f ? a2 : 0.0f;
    }
    __syncthreads();
    if (h < 4) {
        const float4* o24 = (const float4*)(ow2 + h*64);
        const float4* h24 = (const float4*)hid2;
        float dx = ob2[h];
#pragma unroll
        for (int j = 0; j < 16; ++j) {
            float4 wv = o24[j]; float4 hv = h24[j];
            dx += wv.x*hv.x + wv.y*hv.y + wv.z*hv.z + wv.w*hv.w;
        }
        int n = item >> 1, s = item & 1;
        float nx = xt[item*4 + h] + dx;
        xt[item*4 + h] = nx;
        out[((n*TT + tstep)*SS + s)*4 + h] = nx;
    }
}

extern "C" void kernel_launch(void* const* d_in, const int* in_sizes, int n_in,
                              void* d_out, int out_size, void* d_ws, size_t ws_size,
                              hipStream_t stream) {
    const float* inputs = (const float*)d_in[0];
    const float* zA     = (const float*)d_in[1];
    const float* zG     = (const float*)d_in[2];
    const int*   src    = (const int*)d_in[3];
    const int*   dst    = (const int*)d_in[4];
    const float* Ws     = (const float*)d_in[5];
    const float* Wd     = (const float*)d_in[6];
    const float* F2w1   = (const float*)d_in[7];
    const float* F2w2   = (const float*)d_in[8];
    const float* F1w1   = (const float*)d_in[9];
    const float* F1w2   = (const float*)d_in[10];
    const float* xw     = (const float*)d_in[11];
    const float* xb     = (const float*)d_in[12];
    const float* ow1    = (const float*)d_in[13];
    const float* ob1    = (const float*)d_in[14];
    const float* ow2    = (const float*)d_in[15];
    const float* ob2    = (const float*)d_in[16];
    float* out = (float*)d_out;

    // ---- workspace carve (units: floats; persistent first, then phase-union) ----
    float*          base        = (float*)d_ws;
    float*          M           = base;                          // 4,096
    float*          e_arr       = base + 4096;                   // 1,280,000
    unsigned*       mbuf        = (unsigned*)(base + 1284096);   // 80,000 (zeroed)
    float*          denom       = base + 1364096;                // 80,000 (zeroed)
    int*            deg_i       = (int*)(base + 1444096);        // 10,000 (zeroed)
    int*            offsets     = (int*)(base + 1454096);        // 10,001
    int*            cursor      = (int*)(base + 1464112);        // 10,000
    int*            edge_by_dst = (int*)(base + 1474112);        // 160,000
    float*          xt          = base + 1634112;                // 80,000
    float*          res         = base + 1714112;                // 5,120,000
    unsigned short* xtb         = (unsigned short*)(base + 6834112); // 1,280,000 ush
    unsigned short* W1b         = (unsigned short*)(base + 7474112); // 8,192 ush
    unsigned short* W2b         = (unsigned short*)(base + 7478208); // 4,096 ush
    // phase union @ 7,480,256: q (2.56M fl, attention phase) / dA (20.48M ush, step phase)
    float*          q           = base + 7480256;
    unsigned short* dA          = (unsigned short*)(base + 7480256);
    // total: 17,720,256 floats = 70.9 MB

    // zero mbuf+denom+deg_i in one shot (contiguous: 170,000 * 4B)
    hipMemsetAsync(mbuf, 0, 170000u * 4u, stream);

    // ---- attention phase (once) ----
    k_attnM<<<KK*ZZ, ZZ, 0, stream>>>(Ws, Wd, M);
    k_q<<<(NN*SS*KK*ZZ + 255)/256, 256, 0, stream>>>(zG, M, q);
    k_edge_e<<<(NE*SS*KK + 255)/256, 256, 0, stream>>>(q, zG, src, dst, e_arr, mbuf, deg_i);
    k_edge_softmax<<<(NE*SS*KK + 255)/256, 256, 0, stream>>>(dst, e_arr, mbuf, denom);
    k_scan<<<1, 1024, 0, stream>>>(deg_i, offsets, cursor);
    k_scatter<<<(NE + 255)/256, 256, 0, stream>>>(dst, cursor, edge_by_dst);
    k_wconv<<<(HH*2*HH + 255)/256, 256, 0, stream>>>(F2w1, F2w2, W1b, W2b);

    // ---- time stepping ----
    k_xt0<<<(NN*SS*NIN + 255)/256, 256, 0, stream>>>(inputs, xt);
    for (int t = 0; t < 2; ++t) {
        k_xenc<<<(NN*SS*HH + 255)/256, 256, 0, stream>>>(xt, xw, xb, xtb);
        k_edge_mfma<<<NE*SS/64, 256, 0, stream>>>(xtb, W1b, W2b, edge_by_dst, src, dst, dA);
        k_agg<<<NN*SS, 64, 0, stream>>>(dA, edge_by_dst, offsets, e_arr, denom, res);
        k_node_update<<<NN*SS, 64, 0, stream>>>(res, zA, F1w1, F1w2,
                                                ow1, ob1, ow2, ob2, xt, out, t);
    }
}

// Round 4
// 418.569 us; speedup vs baseline: 4.2692x; 2.1065x over previous
//
#include <hip/hip_runtime.h>

#define NN 10000
#define NE 160000
#define TT 2
#define SS 2
#define HH 64
#define ZZ 32
#define KK 4
#define NIN 4

typedef short bf16x8 __attribute__((ext_vector_type(8)));
typedef float f32x4 __attribute__((ext_vector_type(4)));

// ---- monotonic float<->uint encoding for atomicMax on floats ----
__device__ __forceinline__ unsigned enc_f(float f) {
    unsigned u = __float_as_uint(f);
    return (u & 0x80000000u) ? ~u : (u | 0x80000000u);
}
__device__ __forceinline__ float dec_f(unsigned u) {
    return __uint_as_float((u & 0x80000000u) ? (u ^ 0x80000000u) : ~u);
}
// fp32 -> bf16 (RNE)
__device__ __forceinline__ unsigned short f2b(float x) {
    unsigned u = __float_as_uint(x);
    u += 0x7fffu + ((u >> 16) & 1u);
    return (unsigned short)(u >> 16);
}

// A0: M[k][i][j] = sum_h Ws[k,h,i] * Wd[k,h,j]   (grid 128 = K*Z, block 32)
__global__ void k_attnM(const float* __restrict__ Ws, const float* __restrict__ Wd,
                        float* __restrict__ M) {
    int k = blockIdx.x >> 5;
    int i = blockIdx.x & 31;
    int j = threadIdx.x;
    float acc = 0.0f;
    for (int h = 0; h < HH; ++h)
        acc += Ws[(k*HH + h)*ZZ + i] * Wd[(k*HH + h)*ZZ + j];
    M[(k*ZZ + i)*ZZ + j] = acc;
}

// A1: q[n,s,k,j] = sum_i zG[n,s,i] * M[k][i][j]
__global__ void k_q(const float* __restrict__ zG, const float* __restrict__ M,
                    float* __restrict__ q) {
    int t = blockIdx.x * blockDim.x + threadIdx.x;
    if (t >= NN*SS*KK*ZZ) return;
    int j  = t & 31;
    int k  = (t >> 5) & 3;
    int ns = t >> 7;
    const float* zg = zG + ns*ZZ;
    const float* m  = M + k*ZZ*ZZ;
    float acc = 0.0f;
#pragma unroll
    for (int i = 0; i < ZZ; ++i) acc += zg[i] * m[i*ZZ + j];
    q[t] = acc;
}

// A2: e = leaky(dot(q[src,s,k,:], zG[dst,s,:])); atomicMax per (dst,s,k); deg count
__global__ void k_edge_e(const float* __restrict__ q, const float* __restrict__ zG,
                         const int* __restrict__ src, const int* __restrict__ dst,
                         float* __restrict__ e_arr, unsigned* __restrict__ mbuf,
                         int* __restrict__ deg_i) {
    int t = blockIdx.x * blockDim.x + threadIdx.x;
    if (t >= NE*SS*KK) return;
    int k = t & 3;
    int s = (t >> 2) & 1;
    int e = t >> 3;
    int sn = src[e], dn = dst[e];
    const float* qq = q  + ((sn*SS + s)*KK + k)*ZZ;
    const float* zg = zG + (dn*SS + s)*ZZ;
    float acc = 0.0f;
#pragma unroll
    for (int j = 0; j < ZZ; ++j) acc += qq[j] * zg[j];
    float ev = acc > 0.0f ? acc : 0.01f*acc;
    e_arr[t] = ev;
    atomicMax(mbuf + (dn*SS + s)*KK + k, enc_f(ev));
    if ((t & 7) == 0) atomicAdd(deg_i + dn, 1);
}

// A3: ex = exp(e - m[dst]); denom += ex  (e_arr overwritten with ex)
__global__ void k_edge_softmax(const int* __restrict__ dst, float* __restrict__ e_arr,
                               const unsigned* __restrict__ mbuf, float* __restrict__ denom) {
    int t = blockIdx.x * blockDim.x + threadIdx.x;
    if (t >= NE*SS*KK) return;
    int k = t & 3;
    int s = (t >> 2) & 1;
    int e = t >> 3;
    int dn = dst[e];
    float m = dec_f(mbuf[(dn*SS + s)*KK + k]);
    float ex = __expf(e_arr[t] - m);
    e_arr[t] = ex;
    atomicAdd(denom + (dn*SS + s)*KK + k, ex);
}

// C2: exclusive scan of deg_i -> offsets[0..NN], cursor copy (single block, 1024 thr)
__global__ void k_scan(const int* __restrict__ deg_i, int* __restrict__ offsets,
                       int* __restrict__ cursor) {
    __shared__ int part[1024];
    int tidx = threadIdx.x;
    const int CH = (NN + 1023) / 1024;   // 10
    int b0 = tidx * CH;
    int sum = 0;
    for (int i = 0; i < CH; ++i) { int idx = b0 + i; if (idx < NN) sum += deg_i[idx]; }
    part[tidx] = sum;
    __syncthreads();
    if (tidx == 0) {
        int run = 0;
        for (int i = 0; i < 1024; ++i) { int tmp = part[i]; part[i] = run; run += tmp; }
    }
    __syncthreads();
    int run = part[tidx];
    for (int i = 0; i < CH; ++i) {
        int idx = b0 + i;
        if (idx < NN) { offsets[idx] = run; cursor[idx] = run; run += deg_i[idx]; }
    }
    if (tidx == 0) offsets[NN] = NE;
}

// C3: scatter edge ids into dst-sorted order
__global__ void k_scatter(const int* __restrict__ dst, int* __restrict__ cursor,
                          int* __restrict__ edge_by_dst) {
    int e = blockIdx.x * blockDim.x + threadIdx.x;
    if (e >= NE) return;
    int pos = atomicAdd(cursor + dst[e], 1);
    edge_by_dst[pos] = e;
}

// W0: convert all step-phase constants to bf16 (weights + zA)
__global__ void k_conv_all(const float* __restrict__ F2w1, const float* __restrict__ F2w2,
                           const float* __restrict__ F1w1, const float* __restrict__ F1w2,
                           const float* __restrict__ ow1, const float* __restrict__ ow2,
                           const float* __restrict__ zA,
                           unsigned short* __restrict__ W1b, unsigned short* __restrict__ W2b,
                           unsigned short* __restrict__ F1w1b, unsigned short* __restrict__ F1w2b,
                           unsigned short* __restrict__ ow1b, unsigned short* __restrict__ ow2b,
                           unsigned short* __restrict__ zAb) {
    int t = blockIdx.x * blockDim.x + threadIdx.x;
    if (t < NN*SS*ZZ) zAb[t] = f2b(zA[t]);
    if (t < HH*2*HH)  W1b[t] = f2b(F2w1[t]);
    if (t < HH*HH)    { W2b[t] = f2b(F2w2[t]); F1w2b[t] = f2b(F1w2[t]); }
    if (t < HH*KK*HH) F1w1b[t] = f2b(F1w1[t]);
    if (t < HH*(HH+ZZ)) ow1b[t] = f2b(ow1[t]);
    if (t < 4*HH)     ow2b[t] = f2b(ow2[t]);
}

// B0: xt[n,s,i] = inputs[n, 0, i]
__global__ void k_xt0(const float* __restrict__ inputs, float* __restrict__ xt) {
    int t = blockIdx.x * blockDim.x + threadIdx.x;
    if (t >= NN*SS*NIN) return;
    int i = t & 3;
    int n = t >> 3;
    xt[t] = inputs[n*(TT*NIN) + i];
}

// B1: xt_enc (bf16) = xt @ xenc_w.T + b
__global__ void k_xenc(const float* __restrict__ xt, const float* __restrict__ w,
                       const float* __restrict__ b, unsigned short* __restrict__ xtb) {
    int t = blockIdx.x * blockDim.x + threadIdx.x;
    if (t >= NN*SS*HH) return;
    int h  = t & 63;
    int ns = t >> 6;
    const float* x = xt + ns*NIN;
    float acc = b[h];
#pragma unroll
    for (int i = 0; i < NIN; ++i) acc += x[i] * w[h*NIN + i];
    xtb[t] = f2b(acc);
}

// B2: edge MLP as bf16 MFMA GEMM over dst-sorted edge-sample rows.
__global__ __launch_bounds__(256) void k_edge_mfma(
    const unsigned short* __restrict__ xtb, const unsigned short* __restrict__ W1b,
    const unsigned short* __restrict__ W2b, const int* __restrict__ edge_by_dst,
    const int* __restrict__ src, const int* __restrict__ dst,
    unsigned short* __restrict__ dA)
{
    __shared__ unsigned short cat_s[64*136];
    __shared__ unsigned short hid_s[4*16*72];
    int tid = threadIdx.x;
    int w   = tid >> 6;
    int l   = tid & 63;
    int l15 = l & 15;
    int qq  = l >> 4;

    bf16x8 b1[4][4], b2[2][4];
#pragma unroll
    for (int nb = 0; nb < 4; ++nb) {
        int n = nb*16 + l15;
#pragma unroll
        for (int kb = 0; kb < 4; ++kb)
            b1[kb][nb] = *(const bf16x8*)(W1b + n*128 + kb*32 + qq*8);
#pragma unroll
        for (int kb = 0; kb < 2; ++kb)
            b2[kb][nb] = *(const bf16x8*)(W2b + n*64 + kb*32 + qq*8);
    }

    int tile = blockIdx.x;
    {
        int r = tid >> 2, qc = tid & 3;
        int m = tile*64 + r;
        int idx = m >> 1, s = m & 1;
        int e = edge_by_dst[idx];
        int node = (qc < 2) ? src[e] : dst[e];
        const unsigned short* sp = xtb + (node*SS + s)*HH + (qc & 1)*32;
        unsigned short* dp = cat_s + r*136 + qc*32;
        *(uint4*)(dp)      = *(const uint4*)(sp);
        *(uint4*)(dp + 8)  = *(const uint4*)(sp + 8);
        *(uint4*)(dp + 16) = *(const uint4*)(sp + 16);
        *(uint4*)(dp + 24) = *(const uint4*)(sp + 24);
    }
    __syncthreads();

    f32x4 acc[4];
#pragma unroll
    for (int nb = 0; nb < 4; ++nb) acc[nb] = (f32x4)(0.0f);
    const unsigned short* arow = cat_s + (w*16 + l15)*136 + qq*8;
#pragma unroll
    for (int kb = 0; kb < 4; ++kb) {
        bf16x8 af = *(const bf16x8*)(arow + kb*32);
#pragma unroll
        for (int nb = 0; nb < 4; ++nb)
            acc[nb] = __builtin_amdgcn_mfma_f32_16x16x32_bf16(af, b1[kb][nb], acc[nb], 0, 0, 0);
    }

    unsigned short* hw = hid_s + w*16*72;
#pragma unroll
    for (int nb = 0; nb < 4; ++nb)
#pragma unroll
        for (int r = 0; r < 4; ++r) {
            float v = acc[nb][r];
            hw[(qq*4 + r)*72 + nb*16 + l15] = f2b(v > 0.0f ? v : 0.0f);
        }

    f32x4 acc2[4];
#pragma unroll
    for (int nb = 0; nb < 4; ++nb) acc2[nb] = (f32x4)(0.0f);
    const unsigned short* a2row = hid_s + w*16*72 + l15*72 + qq*8;
#pragma unroll
    for (int kb = 0; kb < 2; ++kb) {
        bf16x8 af = *(const bf16x8*)(a2row + kb*32);
#pragma unroll
        for (int nb = 0; nb < 4; ++nb)
            acc2[nb] = __builtin_amdgcn_mfma_f32_16x16x32_bf16(af, b2[kb][nb], acc2[nb], 0, 0, 0);
    }

    unsigned short* drow = dA + (tile*64 + w*16)*64;
#pragma unroll
    for (int nb = 0; nb < 4; ++nb)
#pragma unroll
        for (int r = 0; r < 4; ++r)
            drow[(qq*4 + r)*64 + nb*16 + l15] = f2b(acc2[nb][r]);
}

// B2b: attention-weighted aggregation per (n,s): res_b[item, k*64+h] (bf16 out)
__global__ __launch_bounds__(64) void k_agg(
    const unsigned short* __restrict__ dA, const int* __restrict__ edge_by_dst,
    const int* __restrict__ offsets, const float* __restrict__ exv,
    const float* __restrict__ denom, unsigned short* __restrict__ res_b)
{
    int item = blockIdx.x;
    int n = item >> 1, s = item & 1;
    int h = threadIdx.x;
    int r0 = offsets[n], r1 = offsets[n+1];
    float a0 = 0.f, a1 = 0.f, a2 = 0.f, a3 = 0.f;
    for (int idx = r0; idx < r1; ++idx) {
        int e = edge_by_dst[idx];
        const float4 al = *(const float4*)(exv + (e*SS + s)*KK);
        unsigned short uv = dA[(idx*2 + s)*64 + h];
        float v = __uint_as_float(((unsigned)uv) << 16);
        a0 += al.x*v; a1 += al.y*v; a2 += al.z*v; a3 += al.w*v;
    }
    int degv = r1 - r0;
    float dinvdeg = 1.0f / (float)(degv > 1 ? degv : 1);
    const float4 dn4 = *(const float4*)(denom + item*KK);
    float i0 = dn4.x != 0.f ? 1.f/dn4.x : 0.f;
    float i1 = dn4.y != 0.f ? 1.f/dn4.y : 0.f;
    float i2 = dn4.z != 0.f ? 1.f/dn4.z : 0.f;
    float i3 = dn4.w != 0.f ? 1.f/dn4.w : 0.f;
    res_b[item*256 +       h] = f2b(a0 * dinvdeg * i0);
    res_b[item*256 + 64  + h] = f2b(a1 * dinvdeg * i1);
    res_b[item*256 + 128 + h] = f2b(a2 * dinvdeg * i2);
    res_b[item*256 + 192 + h] = f2b(a3 * dinvdeg * i3);
}

// B3: node update as chained bf16 MFMA GEMMs. 4 waves/block, 16 items/wave.
// LDS: only F1w1 tile (33,792B) + per-wave scratch (22,528B) = 56,320B < 64KiB.
// F1w2 / ow1 / ow2 B-fragments load straight from global (L1/L2-hot).
__global__ __launch_bounds__(256) void k_node_mfma(
    const unsigned short* __restrict__ res_b, const unsigned short* __restrict__ zAb,
    const unsigned short* __restrict__ F1w1b, const unsigned short* __restrict__ F1w2b,
    const unsigned short* __restrict__ ow1b, const unsigned short* __restrict__ ow2b,
    const float* __restrict__ ob1, const float* __restrict__ ob2,
    float* __restrict__ xt, float* __restrict__ out, int tstep)
{
    __shared__ unsigned short w1s[64*264];      // F1w1 rows, stride 264
    __shared__ unsigned short hid_s[4][16*72];  // per-wave scratch
    __shared__ unsigned short hcat_s[4][16*104];
    int tid = threadIdx.x;
    int w = tid >> 6, l = tid & 63, l15 = l & 15, qq = l >> 4;

    // ---- stage F1w1 in LDS (padded stride -> uniform bank groups) ----
    for (int i = tid; i < 64*32; i += 256) {
        int r = i >> 5, c = i & 31;
        *(uint4*)(w1s + r*264 + c*8) = *(const uint4*)(F1w1b + r*256 + c*8);
    }
    // small-weight B-fragments in registers (per-wave redundant, L2-hot)
    bf16x8 b2f[2][4], o1f[3][4], bo2[2];
#pragma unroll
    for (int nb = 0; nb < 4; ++nb) {
        int n = nb*16 + l15;
#pragma unroll
        for (int kb = 0; kb < 2; ++kb)
            b2f[kb][nb] = *(const bf16x8*)(F1w2b + n*64 + kb*32 + qq*8);
#pragma unroll
        for (int kb = 0; kb < 3; ++kb)
            o1f[kb][nb] = *(const bf16x8*)(ow1b + n*96 + kb*32 + qq*8);
    }
#pragma unroll
    for (int kb = 0; kb < 2; ++kb) {
        if (l15 < 4) bo2[kb] = *(const bf16x8*)(ow2b + l15*64 + kb*32 + qq*8);
        else {
            bf16x8 z;
#pragma unroll
            for (int j = 0; j < 8; ++j) z[j] = 0;
            bo2[kb] = z;
        }
    }
    float b1v[4];
#pragma unroll
    for (int nb = 0; nb < 4; ++nb) b1v[nb] = ob1[nb*16 + l15];
    float b2v = (l15 < 4) ? ob2[l15] : 0.0f;
    __syncthreads();

    int itemBase = blockIdx.x*64 + w*16;
    if (itemBase >= NN*SS) return;

    // stage zA into hcat cols 64..95 (16 rows x 32 cols = 64 lanes x 8)
    *(uint4*)(&hcat_s[w][l15*104 + 64 + qq*8]) =
        *(const uint4*)(zAb + (itemBase + l15)*ZZ + qq*8);

    // ---- GEMM1: res[16x256] @ F1w1^T[256x64], relu ----
    f32x4 acc[4];
#pragma unroll
    for (int nb = 0; nb < 4; ++nb) acc[nb] = (f32x4)(0.0f);
#pragma unroll
    for (int kb = 0; kb < 8; ++kb) {
        bf16x8 af = *(const bf16x8*)(res_b + (itemBase + l15)*256 + kb*32 + qq*8);
#pragma unroll
        for (int nb = 0; nb < 4; ++nb) {
            bf16x8 bf = *(const bf16x8*)(w1s + (nb*16 + l15)*264 + kb*32 + qq*8);
            acc[nb] = __builtin_amdgcn_mfma_f32_16x16x32_bf16(af, bf, acc[nb], 0, 0, 0);
        }
    }
#pragma unroll
    for (int nb = 0; nb < 4; ++nb)
#pragma unroll
        for (int r = 0; r < 4; ++r) {
            float v = acc[nb][r];
            hid_s[w][(qq*4 + r)*72 + nb*16 + l15] = f2b(v > 0.0f ? v : 0.0f);
        }

    // ---- GEMM2: hid[16x64] @ F1w2^T[64x64] -> deltax (no relu) -> hcat cols 0..63 ----
    f32x4 acc2[4];
#pragma unroll
    for (int nb = 0; nb < 4; ++nb) acc2[nb] = (f32x4)(0.0f);
#pragma unroll
    for (int kb = 0; kb < 2; ++kb) {
        bf16x8 af = *(const bf16x8*)(&hid_s[w][l15*72 + kb*32 + qq*8]);
#pragma unroll
        for (int nb = 0; nb < 4; ++nb)
            acc2[nb] = __builtin_amdgcn_mfma_f32_16x16x32_bf16(af, b2f[kb][nb], acc2[nb], 0, 0, 0);
    }
#pragma unroll
    for (int nb = 0; nb < 4; ++nb)
#pragma unroll
        for (int r = 0; r < 4; ++r)
            hcat_s[w][(qq*4 + r)*104 + nb*16 + l15] = f2b(acc2[nb][r]);

    // ---- GEMM3: hcat[16x96] @ ow1^T[96x64] + b1, relu -> hid_s ----
    f32x4 acc3[4];
#pragma unroll
    for (int nb = 0; nb < 4; ++nb) acc3[nb] = (f32x4)(0.0f);
#pragma unroll
    for (int kb = 0; kb < 3; ++kb) {
        bf16x8 af = *(const bf16x8*)(&hcat_s[w][l15*104 + kb*32 + qq*8]);
#pragma unroll
        for (int nb = 0; nb < 4; ++nb)
            acc3[nb] = __builtin_amdgcn_mfma_f32_16x16x32_bf16(af, o1f[kb][nb], acc3[nb], 0, 0, 0);
    }
#pragma unroll
    for (int nb = 0; nb < 4; ++nb)
#pragma unroll
        for (int r = 0; r < 4; ++r) {
            float v = acc3[nb][r] + b1v[nb];
            hid_s[w][(qq*4 + r)*72 + nb*16 + l15] = f2b(v > 0.0f ? v : 0.0f);
        }

    // ---- GEMM4: hid[16x64] @ ow2^T[64x4(pad16)] + b2 ----
    f32x4 acc4 = (f32x4)(0.0f);
#pragma unroll
    for (int kb = 0; kb < 2; ++kb) {
        bf16x8 af = *(const bf16x8*)(&hid_s[w][l15*72 + kb*32 + qq*8]);
        acc4 = __builtin_amdgcn_mfma_f32_16x16x32_bf16(af, bo2[kb], acc4, 0, 0, 0);
    }
    if (l15 < 4) {
#pragma unroll
        for (int r = 0; r < 4; ++r) {
            int item = itemBase + qq*4 + r;
            float nx = xt[item*4 + l15] + acc4[r] + b2v;
            xt[item*4 + l15] = nx;
            int n = item >> 1, s = item & 1;
            out[((n*TT + tstep)*SS + s)*4 + l15] = nx;
        }
    }
}

extern "C" void kernel_launch(void* const* d_in, const int* in_sizes, int n_in,
                              void* d_out, int out_size, void* d_ws, size_t ws_size,
                              hipStream_t stream) {
    const float* inputs = (const float*)d_in[0];
    const float* zA     = (const float*)d_in[1];
    const float* zG     = (const float*)d_in[2];
    const int*   src    = (const int*)d_in[3];
    const int*   dst    = (const int*)d_in[4];
    const float* Ws     = (const float*)d_in[5];
    const float* Wd     = (const float*)d_in[6];
    const float* F2w1   = (const float*)d_in[7];
    const float* F2w2   = (const float*)d_in[8];
    const float* F1w1   = (const float*)d_in[9];
    const float* F1w2   = (const float*)d_in[10];
    const float* xw     = (const float*)d_in[11];
    const float* xb     = (const float*)d_in[12];
    const float* ow1    = (const float*)d_in[13];
    const float* ob1    = (const float*)d_in[14];
    const float* ow2    = (const float*)d_in[15];
    const float* ob2    = (const float*)d_in[16];
    float* out = (float*)d_out;

    // ---- workspace carve (units: floats; all offsets 64B-aligned) ----
    float*          base        = (float*)d_ws;
    float*          M           = base;                              // 4,096
    float*          e_arr       = base + 4096;                       // 1,280,000
    unsigned*       mbuf        = (unsigned*)(base + 1284096);       // 80,000 (zeroed)
    float*          denom       = base + 1364096;                    // 80,000 (zeroed)
    int*            deg_i       = (int*)(base + 1444096);            // 10,000 (zeroed)
    int*            offsets     = (int*)(base + 1454096);            // 10,016
    int*            cursor      = (int*)(base + 1464112);            // 10,000
    int*            edge_by_dst = (int*)(base + 1474112);            // 160,000
    float*          xt          = base + 1634112;                    // 80,000
    unsigned short* xtb         = (unsigned short*)(base + 1714112); // 1,280,000 ush
    unsigned short* W1b         = (unsigned short*)(base + 2354112); // 8,192 ush
    unsigned short* W2b         = (unsigned short*)(base + 2358208); // 4,096 ush
    unsigned short* F1w1b       = (unsigned short*)(base + 2360256); // 16,384 ush
    unsigned short* F1w2b       = (unsigned short*)(base + 2368448); // 4,096 ush
    unsigned short* ow1b        = (unsigned short*)(base + 2370496); // 6,144 ush
    unsigned short* ow2b        = (unsigned short*)(base + 2373568); // 256 ush
    unsigned short* zAb         = (unsigned short*)(base + 2373696); // 640,000 ush
    unsigned short* res_b       = (unsigned short*)(base + 2693696); // 5,120,000 ush
    // phase union @ 5,253,696: q (2.56M fl, attention) / dA (20.48M ush, steps)
    float*          q           = base + 5253696;
    unsigned short* dA          = (unsigned short*)(base + 5253696);
    // total 15,493,696 floats = 62.0 MB

    hipMemsetAsync(mbuf, 0, 170000u * 4u, stream);

    // ---- attention phase (once) ----
    k_attnM<<<KK*ZZ, ZZ, 0, stream>>>(Ws, Wd, M);
    k_q<<<(NN*SS*KK*ZZ + 255)/256, 256, 0, stream>>>(zG, M, q);
    k_edge_e<<<(NE*SS*KK + 255)/256, 256, 0, stream>>>(q, zG, src, dst, e_arr, mbuf, deg_i);
    k_edge_softmax<<<(NE*SS*KK + 255)/256, 256, 0, stream>>>(dst, e_arr, mbuf, denom);
    k_scan<<<1, 1024, 0, stream>>>(deg_i, offsets, cursor);
    k_scatter<<<(NE + 255)/256, 256, 0, stream>>>(dst, cursor, edge_by_dst);
    k_conv_all<<<(NN*SS*ZZ + 255)/256, 256, 0, stream>>>(F2w1, F2w2, F1w1, F1w2, ow1, ow2, zA,
                                                         W1b, W2b, F1w1b, F1w2b, ow1b, ow2b, zAb);

    // ---- time stepping ----
    k_xt0<<<(NN*SS*NIN + 255)/256, 256, 0, stream>>>(inputs, xt);
    for (int t = 0; t < 2; ++t) {
        k_xenc<<<(NN*SS*HH + 255)/256, 256, 0, stream>>>(xt, xw, xb, xtb);
        k_edge_mfma<<<NE*SS/64, 256, 0, stream>>>(xtb, W1b, W2b, edge_by_dst, src, dst, dA);
        k_agg<<<NN*SS, 64, 0, stream>>>(dA, edge_by_dst, offsets, e_arr, denom, res_b);
        k_node_mfma<<<(NN*SS + 63)/64, 256, 0, stream>>>(res_b, zAb, F1w1b, F1w2b,
                                                         ow1b, ow2b, ob1, ob2, xt, out, t);
    }
}

// Round 5
// 369.838 us; speedup vs baseline: 4.8317x; 1.1318x over previous
//
#include <hip/hip_runtime.h>

#define NN 10000
#define NE 160000
#define TT 2
#define SS 2
#define HH 64
#define ZZ 32
#define KK 4
#define NIN 4

typedef short bf16x8 __attribute__((ext_vector_type(8)));
typedef float f32x4 __attribute__((ext_vector_type(4)));

// fp32 -> bf16 (RNE)
__device__ __forceinline__ unsigned short f2b(float x) {
    unsigned u = __float_as_uint(x);
    u += 0x7fffu + ((u >> 16) & 1u);
    return (unsigned short)(u >> 16);
}

// A0: M[k][i][j] = sum_h Ws[k,h,i] * Wd[k,h,j]   (grid 128 = K*Z, block 32)
__global__ void k_attnM(const float* __restrict__ Ws, const float* __restrict__ Wd,
                        float* __restrict__ M) {
    int k = blockIdx.x >> 5;
    int i = blockIdx.x & 31;
    int j = threadIdx.x;
    float acc = 0.0f;
    for (int h = 0; h < HH; ++h)
        acc += Ws[(k*HH + h)*ZZ + i] * Wd[(k*HH + h)*ZZ + j];
    M[(k*ZZ + i)*ZZ + j] = acc;
}

// A1: q[n,s,k,j] = sum_i zG[n,s,i] * M[k][i][j]
__global__ void k_q(const float* __restrict__ zG, const float* __restrict__ M,
                    float* __restrict__ q) {
    int t = blockIdx.x * blockDim.x + threadIdx.x;
    if (t >= NN*SS*KK*ZZ) return;
    int j  = t & 31;
    int k  = (t >> 5) & 3;
    int ns = t >> 7;
    const float* zg = zG + ns*ZZ;
    const float* m  = M + k*ZZ*ZZ;
    float acc = 0.0f;
#pragma unroll
    for (int i = 0; i < ZZ; ++i) acc += zg[i] * m[i*ZZ + j];
    q[t] = acc;
}

// A2: one thread per (e,s): e[k] = leaky(dot(q[src,s,k,:], zG[dst,s,:])), k=0..3.
// No atomics except deg count (160k adds).
__global__ void k_edge_e(const float* __restrict__ q, const float* __restrict__ zG,
                         const int* __restrict__ src, const int* __restrict__ dst,
                         float* __restrict__ e_arr, int* __restrict__ deg_i) {
    int t = blockIdx.x * blockDim.x + threadIdx.x;
    if (t >= NE*SS) return;
    int s = t & 1;
    int e = t >> 1;
    int sn = src[e], dn = dst[e];
    const float* zg = zG + (dn*SS + s)*ZZ;
    const float* qq = q  + ((sn*SS + s)*KK)*ZZ;
    float a0 = 0.f, a1 = 0.f, a2 = 0.f, a3 = 0.f;
#pragma unroll
    for (int j = 0; j < ZZ; ++j) {
        float z = zg[j];
        a0 += qq[j]*z; a1 += qq[ZZ + j]*z; a2 += qq[2*ZZ + j]*z; a3 += qq[3*ZZ + j]*z;
    }
    float4 ev;
    ev.x = a0 > 0.f ? a0 : 0.01f*a0;
    ev.y = a1 > 0.f ? a1 : 0.01f*a1;
    ev.z = a2 > 0.f ? a2 : 0.01f*a2;
    ev.w = a3 > 0.f ? a3 : 0.01f*a3;
    *(float4*)(e_arr + e*8 + s*4) = ev;
    if (s == 0) atomicAdd(deg_i + dn, 1);
}

// C2: exclusive scan of deg_i -> offsets[0..NN], cursor copy (single block, 1024 thr)
__global__ void k_scan(const int* __restrict__ deg_i, int* __restrict__ offsets,
                       int* __restrict__ cursor) {
    __shared__ int part[1024];
    int tidx = threadIdx.x;
    const int CH = (NN + 1023) / 1024;   // 10
    int b0 = tidx * CH;
    int sum = 0;
    for (int i = 0; i < CH; ++i) { int idx = b0 + i; if (idx < NN) sum += deg_i[idx]; }
    part[tidx] = sum;
    __syncthreads();
    if (tidx == 0) {
        int run = 0;
        for (int i = 0; i < 1024; ++i) { int tmp = part[i]; part[i] = run; run += tmp; }
    }
    __syncthreads();
    int run = part[tidx];
    for (int i = 0; i < CH; ++i) {
        int idx = b0 + i;
        if (idx < NN) { offsets[idx] = run; cursor[idx] = run; run += deg_i[idx]; }
    }
    if (tidx == 0) offsets[NN] = NE;
}

// C3: scatter edge ids into dst-sorted order
__global__ void k_scatter(const int* __restrict__ dst, int* __restrict__ cursor,
                          int* __restrict__ edge_by_dst) {
    int e = blockIdx.x * blockDim.x + threadIdx.x;
    if (e >= NE) return;
    int pos = atomicAdd(cursor + dst[e], 1);
    edge_by_dst[pos] = e;
}

// A3': per-(n,s) softmax stats via CSR (no atomics): m_arr/inv_den [item,k]
__global__ __launch_bounds__(64) void k_softmax_csr(
    const float* __restrict__ e_arr, const int* __restrict__ edge_by_dst,
    const int* __restrict__ offsets, float* __restrict__ m_arr,
    float* __restrict__ inv_den) {
    int item = blockIdx.x;
    int n = item >> 1, s = item & 1;
    int l = threadIdx.x;
    int i = l >> 2, k = l & 3;
    int r0 = offsets[n], r1 = offsets[n+1];
    float mx = -1e30f;
    for (int idx = r0 + i; idx < r1; idx += 16) {
        int e = edge_by_dst[idx];
        mx = fmaxf(mx, e_arr[e*8 + s*4 + k]);
    }
#pragma unroll
    for (int off = 4; off < 64; off <<= 1) mx = fmaxf(mx, __shfl_xor(mx, off));
    float sum = 0.f;
    for (int idx = r0 + i; idx < r1; idx += 16) {
        int e = edge_by_dst[idx];
        sum += __expf(e_arr[e*8 + s*4 + k] - mx);
    }
#pragma unroll
    for (int off = 4; off < 64; off <<= 1) sum += __shfl_xor(sum, off);
    if (l < 4) {
        m_arr[item*4 + l] = mx;
        inv_den[item*4 + l] = sum > 0.f ? 1.f/sum : 0.f;
    }
}

// W0: convert all step-phase constants to bf16 (weights + zA)
__global__ void k_conv_all(const float* __restrict__ F2w1, const float* __restrict__ F2w2,
                           const float* __restrict__ F1w1, const float* __restrict__ F1w2,
                           const float* __restrict__ ow1, const float* __restrict__ ow2,
                           const float* __restrict__ zA,
                           unsigned short* __restrict__ W1b, unsigned short* __restrict__ W2b,
                           unsigned short* __restrict__ F1w1b, unsigned short* __restrict__ F1w2b,
                           unsigned short* __restrict__ ow1b, unsigned short* __restrict__ ow2b,
                           unsigned short* __restrict__ zAb) {
    int t = blockIdx.x * blockDim.x + threadIdx.x;
    if (t < NN*SS*ZZ) zAb[t] = f2b(zA[t]);
    if (t < HH*2*HH)  W1b[t] = f2b(F2w1[t]);
    if (t < HH*HH)    { W2b[t] = f2b(F2w2[t]); F1w2b[t] = f2b(F1w2[t]); }
    if (t < HH*KK*HH) F1w1b[t] = f2b(F1w1[t]);
    if (t < HH*(HH+ZZ)) ow1b[t] = f2b(ow1[t]);
    if (t < 4*HH)     ow2b[t] = f2b(ow2[t]);
}

// B0: xt[n,s,i] = inputs[n, 0, i]
__global__ void k_xt0(const float* __restrict__ inputs, float* __restrict__ xt) {
    int t = blockIdx.x * blockDim.x + threadIdx.x;
    if (t >= NN*SS*NIN) return;
    int i = t & 3;
    int n = t >> 3;
    xt[t] = inputs[n*(TT*NIN) + i];
}

// B1: xt_enc (bf16) = xt @ xenc_w.T + b
__global__ void k_xenc(const float* __restrict__ xt, const float* __restrict__ w,
                       const float* __restrict__ b, unsigned short* __restrict__ xtb) {
    int t = blockIdx.x * blockDim.x + threadIdx.x;
    if (t >= NN*SS*HH) return;
    int h  = t & 63;
    int ns = t >> 6;
    const float* x = xt + ns*NIN;
    float acc = b[h];
#pragma unroll
    for (int i = 0; i < NIN; ++i) acc += x[i] * w[h*NIN + i];
    xtb[t] = f2b(acc);
}

// B2 v2: edge MLP MFMA GEMM, barrier-free direct-gather A-fragments,
// persistent grid-stride blocks, 2-stage software pipeline.
__global__ __launch_bounds__(256) void k_edge_mfma(
    const unsigned short* __restrict__ xtb, const unsigned short* __restrict__ W1b,
    const unsigned short* __restrict__ W2b, const int* __restrict__ edge_by_dst,
    const int* __restrict__ src, const int* __restrict__ dst,
    unsigned short* __restrict__ dA)
{
    __shared__ unsigned short hid_s[4][16*72];   // per-wave only; no block barrier
    const int NT = NE*SS/64;   // 5000 tiles
    int tid = threadIdx.x;
    int w = tid >> 6, l = tid & 63, l15 = l & 15, qq = l >> 4;
    int s = l15 & 1;
    int eslot = w*8 + (l15 >> 1);   // edge slot within tile (2 rows/edge)

    // weight B-fragments, loaded ONCE per block
    bf16x8 b1[4][4], b2[2][4];
#pragma unroll
    for (int nb = 0; nb < 4; ++nb) {
        int n = nb*16 + l15;
#pragma unroll
        for (int kb = 0; kb < 4; ++kb)
            b1[kb][nb] = *(const bf16x8*)(W1b + n*128 + kb*32 + qq*8);
#pragma unroll
        for (int kb = 0; kb < 2; ++kb)
            b2[kb][nb] = *(const bf16x8*)(W2b + n*64 + kb*32 + qq*8);
    }

    int G = gridDim.x;
    int t = blockIdx.x;

    // ---- prologue: ids(t) -> data(t); ids(t+G) ----
    int e0 = edge_by_dst[t*32 + eslot];
    int sn0 = src[e0], dn0 = dst[e0];
    const unsigned short* ps = xtb + (sn0*SS + s)*HH + qq*8;
    const unsigned short* pd = xtb + (dn0*SS + s)*HH + qq*8;
    bf16x8 a0 = *(const bf16x8*)(ps);
    bf16x8 a1 = *(const bf16x8*)(ps + 32);
    bf16x8 a2 = *(const bf16x8*)(pd);
    bf16x8 a3 = *(const bf16x8*)(pd + 32);
    int t1 = t + G;
    int tc1 = t1 < NT ? t1 : 0;
    int e1 = edge_by_dst[tc1*32 + eslot];
    int sn1 = src[e1], dn1 = dst[e1];

    for (; t < NT; t += G) {
        // issue next tile's data gathers (stay in flight through this tile's MFMAs)
        const unsigned short* ps1 = xtb + (sn1*SS + s)*HH + qq*8;
        const unsigned short* pd1 = xtb + (dn1*SS + s)*HH + qq*8;
        bf16x8 n0 = *(const bf16x8*)(ps1);
        bf16x8 n1 = *(const bf16x8*)(ps1 + 32);
        bf16x8 n2 = *(const bf16x8*)(pd1);
        bf16x8 n3 = *(const bf16x8*)(pd1 + 32);
        // issue ids for t+2G
        int t2 = t + 2*G;
        int tc2 = t2 < NT ? t2 : 0;
        int e2 = edge_by_dst[tc2*32 + eslot];
        int sn2 = src[e2], dn2 = dst[e2];

        // ---- GEMM1: cat[16x128] @ W1^T[128x64] ----
        f32x4 acc[4];
#pragma unroll
        for (int nb = 0; nb < 4; ++nb) acc[nb] = (f32x4)(0.0f);
#pragma unroll
        for (int nb = 0; nb < 4; ++nb) {
            acc[nb] = __builtin_amdgcn_mfma_f32_16x16x32_bf16(a0, b1[0][nb], acc[nb], 0, 0, 0);
            acc[nb] = __builtin_amdgcn_mfma_f32_16x16x32_bf16(a1, b1[1][nb], acc[nb], 0, 0, 0);
            acc[nb] = __builtin_amdgcn_mfma_f32_16x16x32_bf16(a2, b1[2][nb], acc[nb], 0, 0, 0);
            acc[nb] = __builtin_amdgcn_mfma_f32_16x16x32_bf16(a3, b1[3][nb], acc[nb], 0, 0, 0);
        }
        // relu -> per-wave LDS (C-layout -> A-layout transpose)
        unsigned short* hw = hid_s[w];
#pragma unroll
        for (int nb = 0; nb < 4; ++nb)
#pragma unroll
            for (int r = 0; r < 4; ++r) {
                float v = acc[nb][r];
                hw[(qq*4 + r)*72 + nb*16 + l15] = f2b(v > 0.0f ? v : 0.0f);
            }
        // ---- GEMM2: hid[16x64] @ W2^T[64x64] ----
        f32x4 acc2[4];
#pragma unroll
        for (int nb = 0; nb < 4; ++nb) acc2[nb] = (f32x4)(0.0f);
        const unsigned short* a2row = hw + l15*72 + qq*8;
#pragma unroll
        for (int kb = 0; kb < 2; ++kb) {
            bf16x8 af = *(const bf16x8*)(a2row + kb*32);
#pragma unroll
            for (int nb = 0; nb < 4; ++nb)
                acc2[nb] = __builtin_amdgcn_mfma_f32_16x16x32_bf16(af, b2[kb][nb], acc2[nb], 0, 0, 0);
        }
        // write dA
        unsigned short* drow = dA + (t*64 + w*16)*64;
#pragma unroll
        for (int nb = 0; nb < 4; ++nb)
#pragma unroll
            for (int r = 0; r < 4; ++r)
                drow[(qq*4 + r)*64 + nb*16 + l15] = f2b(acc2[nb][r]);

        // pipeline shift
        a0 = n0; a1 = n1; a2 = n2; a3 = n3;
        sn1 = sn2; dn1 = dn2;
    }
}

// B2b: aggregation per (n,s); alpha = exp(e-m)*inv_den on the fly; bf16 out
__global__ __launch_bounds__(64) void k_agg(
    const unsigned short* __restrict__ dA, const int* __restrict__ edge_by_dst,
    const int* __restrict__ offsets, const float* __restrict__ e_arr,
    const float* __restrict__ m_arr, const float* __restrict__ inv_den,
    unsigned short* __restrict__ res_b)
{
    int item = blockIdx.x;
    int n = item >> 1, s = item & 1;
    int h = threadIdx.x;
    int r0 = offsets[n], r1 = offsets[n+1];
    const float4 m4 = *(const float4*)(m_arr + item*4);
    const float4 d4 = *(const float4*)(inv_den + item*4);
    float a0 = 0.f, a1 = 0.f, a2 = 0.f, a3 = 0.f;
    for (int idx = r0; idx < r1; ++idx) {
        int e = edge_by_dst[idx];
        const float4 ev = *(const float4*)(e_arr + e*8 + s*4);
        float w0 = __expf(ev.x - m4.x) * d4.x;
        float w1 = __expf(ev.y - m4.y) * d4.y;
        float w2 = __expf(ev.z - m4.z) * d4.z;
        float w3 = __expf(ev.w - m4.w) * d4.w;
        unsigned short uv = dA[(idx*2 + s)*64 + h];
        float v = __uint_as_float(((unsigned)uv) << 16);
        a0 += w0*v; a1 += w1*v; a2 += w2*v; a3 += w3*v;
    }
    int degv = r1 - r0;
    float dinvdeg = 1.0f / (float)(degv > 1 ? degv : 1);
    res_b[item*256 +       h] = f2b(a0 * dinvdeg);
    res_b[item*256 + 64  + h] = f2b(a1 * dinvdeg);
    res_b[item*256 + 128 + h] = f2b(a2 * dinvdeg);
    res_b[item*256 + 192 + h] = f2b(a3 * dinvdeg);
}

// B3: node update as chained bf16 MFMA GEMMs. 4 waves/block, 16 items/wave.
__global__ __launch_bounds__(256) void k_node_mfma(
    const unsigned short* __restrict__ res_b, const unsigned short* __restrict__ zAb,
    const unsigned short* __restrict__ F1w1b, const unsigned short* __restrict__ F1w2b,
    const unsigned short* __restrict__ ow1b, const unsigned short* __restrict__ ow2b,
    const float* __restrict__ ob1, const float* __restrict__ ob2,
    float* __restrict__ xt, float* __restrict__ out, int tstep)
{
    __shared__ unsigned short w1s[64*264];
    __shared__ unsigned short hid_s[4][16*72];
    __shared__ unsigned short hcat_s[4][16*104];
    int tid = threadIdx.x;
    int w = tid >> 6, l = tid & 63, l15 = l & 15, qq = l >> 4;

    for (int i = tid; i < 64*32; i += 256) {
        int r = i >> 5, c = i & 31;
        *(uint4*)(w1s + r*264 + c*8) = *(const uint4*)(F1w1b + r*256 + c*8);
    }
    bf16x8 b2f[2][4], o1f[3][4], bo2[2];
#pragma unroll
    for (int nb = 0; nb < 4; ++nb) {
        int n = nb*16 + l15;
#pragma unroll
        for (int kb = 0; kb < 2; ++kb)
            b2f[kb][nb] = *(const bf16x8*)(F1w2b + n*64 + kb*32 + qq*8);
#pragma unroll
        for (int kb = 0; kb < 3; ++kb)
            o1f[kb][nb] = *(const bf16x8*)(ow1b + n*96 + kb*32 + qq*8);
    }
#pragma unroll
    for (int kb = 0; kb < 2; ++kb) {
        if (l15 < 4) bo2[kb] = *(const bf16x8*)(ow2b + l15*64 + kb*32 + qq*8);
        else {
            bf16x8 z;
#pragma unroll
            for (int j = 0; j < 8; ++j) z[j] = 0;
            bo2[kb] = z;
        }
    }
    float b1v[4];
#pragma unroll
    for (int nb = 0; nb < 4; ++nb) b1v[nb] = ob1[nb*16 + l15];
    float b2v = (l15 < 4) ? ob2[l15] : 0.0f;
    __syncthreads();

    int itemBase = blockIdx.x*64 + w*16;
    if (itemBase >= NN*SS) return;

    *(uint4*)(&hcat_s[w][l15*104 + 64 + qq*8]) =
        *(const uint4*)(zAb + (itemBase + l15)*ZZ + qq*8);

    f32x4 acc[4];
#pragma unroll
    for (int nb = 0; nb < 4; ++nb) acc[nb] = (f32x4)(0.0f);
#pragma unroll
    for (int kb = 0; kb < 8; ++kb) {
        bf16x8 af = *(const bf16x8*)(res_b + (itemBase + l15)*256 + kb*32 + qq*8);
#pragma unroll
        for (int nb = 0; nb < 4; ++nb) {
            bf16x8 bf = *(const bf16x8*)(w1s + (nb*16 + l15)*264 + kb*32 + qq*8);
            acc[nb] = __builtin_amdgcn_mfma_f32_16x16x32_bf16(af, bf, acc[nb], 0, 0, 0);
        }
    }
#pragma unroll
    for (int nb = 0; nb < 4; ++nb)
#pragma unroll
        for (int r = 0; r < 4; ++r) {
            float v = acc[nb][r];
            hid_s[w][(qq*4 + r)*72 + nb*16 + l15] = f2b(v > 0.0f ? v : 0.0f);
        }

    f32x4 acc2[4];
#pragma unroll
    for (int nb = 0; nb < 4; ++nb) acc2[nb] = (f32x4)(0.0f);
#pragma unroll
    for (int kb = 0; kb < 2; ++kb) {
        bf16x8 af = *(const bf16x8*)(&hid_s[w][l15*72 + kb*32 + qq*8]);
#pragma unroll
        for (int nb = 0; nb < 4; ++nb)
            acc2[nb] = __builtin_amdgcn_mfma_f32_16x16x32_bf16(af, b2f[kb][nb], acc2[nb], 0, 0, 0);
    }
#pragma unroll
    for (int nb = 0; nb < 4; ++nb)
#pragma unroll
        for (int r = 0; r < 4; ++r)
            hcat_s[w][(qq*4 + r)*104 + nb*16 + l15] = f2b(acc2[nb][r]);

    f32x4 acc3[4];
#pragma unroll
    for (int nb = 0; nb < 4; ++nb) acc3[nb] = (f32x4)(0.0f);
#pragma unroll
    for (int kb = 0; kb < 3; ++kb) {
        bf16x8 af = *(const bf16x8*)(&hcat_s[w][l15*104 + kb*32 + qq*8]);
#pragma unroll
        for (int nb = 0; nb < 4; ++nb)
            acc3[nb] = __builtin_amdgcn_mfma_f32_16x16x32_bf16(af, o1f[kb][nb], acc3[nb], 0, 0, 0);
    }
#pragma unroll
    for (int nb = 0; nb < 4; ++nb)
#pragma unroll
        for (int r = 0; r < 4; ++r) {
            float v = acc3[nb][r] + b1v[nb];
            hid_s[w][(qq*4 + r)*72 + nb*16 + l15] = f2b(v > 0.0f ? v : 0.0f);
        }

    f32x4 acc4 = (f32x4)(0.0f);
#pragma unroll
    for (int kb = 0; kb < 2; ++kb) {
        bf16x8 af = *(const bf16x8*)(&hid_s[w][l15*72 + kb*32 + qq*8]);
        acc4 = __builtin_amdgcn_mfma_f32_16x16x32_bf16(af, bo2[kb], acc4, 0, 0, 0);
    }
    if (l15 < 4) {
#pragma unroll
        for (int r = 0; r < 4; ++r) {
            int item = itemBase + qq*4 + r;
            float nx = xt[item*4 + l15] + acc4[r] + b2v;
            xt[item*4 + l15] = nx;
            int n = item >> 1, s = item & 1;
            out[((n*TT + tstep)*SS + s)*4 + l15] = nx;
        }
    }
}

extern "C" void kernel_launch(void* const* d_in, const int* in_sizes, int n_in,
                              void* d_out, int out_size, void* d_ws, size_t ws_size,
                              hipStream_t stream) {
    const float* inputs = (const float*)d_in[0];
    const float* zA     = (const float*)d_in[1];
    const float* zG     = (const float*)d_in[2];
    const int*   src    = (const int*)d_in[3];
    const int*   dst    = (const int*)d_in[4];
    const float* Ws     = (const float*)d_in[5];
    const float* Wd     = (const float*)d_in[6];
    const float* F2w1   = (const float*)d_in[7];
    const float* F2w2   = (const float*)d_in[8];
    const float* F1w1   = (const float*)d_in[9];
    const float* F1w2   = (const float*)d_in[10];
    const float* xw     = (const float*)d_in[11];
    const float* xb     = (const float*)d_in[12];
    const float* ow1    = (const float*)d_in[13];
    const float* ob1    = (const float*)d_in[14];
    const float* ow2    = (const float*)d_in[15];
    const float* ob2    = (const float*)d_in[16];
    float* out = (float*)d_out;

    // ---- workspace carve (units: floats) ----
    float*          base        = (float*)d_ws;
    float*          M           = base;                              // 4,096
    float*          e_arr       = base + 4096;                       // 1,280,000
    float*          m_arr       = base + 1284096;                    // 80,000
    float*          inv_den     = base + 1364096;                    // 80,000
    int*            deg_i       = (int*)(base + 1444096);            // 10,000 (zeroed)
    int*            offsets     = (int*)(base + 1454096);            // 10,016
    int*            cursor      = (int*)(base + 1464112);            // 10,000
    int*            edge_by_dst = (int*)(base + 1474112);            // 160,000
    float*          xt          = base + 1634112;                    // 80,000
    unsigned short* xtb         = (unsigned short*)(base + 1714112); // 1,280,000 ush
    unsigned short* W1b         = (unsigned short*)(base + 2354112); // 8,192 ush
    unsigned short* W2b         = (unsigned short*)(base + 2358208); // 4,096 ush
    unsigned short* F1w1b       = (unsigned short*)(base + 2360256); // 16,384 ush
    unsigned short* F1w2b       = (unsigned short*)(base + 2368448); // 4,096 ush
    unsigned short* ow1b        = (unsigned short*)(base + 2370496); // 6,144 ush
    unsigned short* ow2b        = (unsigned short*)(base + 2373568); // 256 ush
    unsigned short* zAb         = (unsigned short*)(base + 2373696); // 640,000 ush
    unsigned short* res_b       = (unsigned short*)(base + 2693696); // 5,120,000 ush
    // phase union @ 5,253,696: q (attention) / dA (steps)
    float*          q           = base + 5253696;
    unsigned short* dA          = (unsigned short*)(base + 5253696);

    hipMemsetAsync(deg_i, 0, 10000u * 4u, stream);

    // ---- attention phase (once) ----
    k_attnM<<<KK*ZZ, ZZ, 0, stream>>>(Ws, Wd, M);
    k_q<<<(NN*SS*KK*ZZ + 255)/256, 256, 0, stream>>>(zG, M, q);
    k_edge_e<<<(NE*SS + 255)/256, 256, 0, stream>>>(q, zG, src, dst, e_arr, deg_i);
    k_scan<<<1, 1024, 0, stream>>>(deg_i, offsets, cursor);
    k_scatter<<<(NE + 255)/256, 256, 0, stream>>>(dst, cursor, edge_by_dst);
    k_softmax_csr<<<NN*SS, 64, 0, stream>>>(e_arr, edge_by_dst, offsets, m_arr, inv_den);
    k_conv_all<<<(NN*SS*ZZ + 255)/256, 256, 0, stream>>>(F2w1, F2w2, F1w1, F1w2, ow1, ow2, zA,
                                                         W1b, W2b, F1w1b, F1w2b, ow1b, ow2b, zAb);

    // ---- time stepping ----
    k_xt0<<<(NN*SS*NIN + 255)/256, 256, 0, stream>>>(inputs, xt);
    for (int t = 0; t < 2; ++t) {
        k_xenc<<<(NN*SS*HH + 255)/256, 256, 0, stream>>>(xt, xw, xb, xtb);
        k_edge_mfma<<<1024, 256, 0, stream>>>(xtb, W1b, W2b, edge_by_dst, src, dst, dA);
        k_agg<<<NN*SS, 64, 0, stream>>>(dA, edge_by_dst, offsets, e_arr, m_arr, inv_den, res_b);
        k_node_mfma<<<(NN*SS + 63)/64, 256, 0, stream>>>(res_b, zAb, F1w1b, F1w2b,
                                                         ow1b, ow2b, ob1, ob2, xt, out, t);
    }
}

// Round 6
// 317.840 us; speedup vs baseline: 5.6222x; 1.1636x over previous
//
#include <hip/hip_runtime.h>

#define NN 10000
#define NE 160000
#define TT 2
#define SS 2
#define HH 64
#define ZZ 32
#define KK 4
#define NIN 4

typedef short bf16x8 __attribute__((ext_vector_type(8)));
typedef float f32x4 __attribute__((ext_vector_type(4)));

// fp32 -> bf16 (RNE)
__device__ __forceinline__ unsigned short f2b(float x) {
    unsigned u = __float_as_uint(x);
    u += 0x7fffu + ((u >> 16) & 1u);
    return (unsigned short)(u >> 16);
}

// A0: M[k][i][j] = sum_h Ws[k,h,i] * Wd[k,h,j]   (grid 128 = K*Z, block 32)
__global__ void k_attnM(const float* __restrict__ Ws, const float* __restrict__ Wd,
                        float* __restrict__ M) {
    int k = blockIdx.x >> 5;
    int i = blockIdx.x & 31;
    int j = threadIdx.x;
    float acc = 0.0f;
    for (int h = 0; h < HH; ++h)
        acc += Ws[(k*HH + h)*ZZ + i] * Wd[(k*HH + h)*ZZ + j];
    M[(k*ZZ + i)*ZZ + j] = acc;
}

// A1: qb[n,s,k,j] (bf16) = sum_i zG[n,s,i] * M[k][i][j]
__global__ void k_q(const float* __restrict__ zG, const float* __restrict__ M,
                    unsigned short* __restrict__ qb) {
    int t = blockIdx.x * blockDim.x + threadIdx.x;
    if (t >= NN*SS*KK*ZZ) return;
    int j  = t & 31;
    int k  = (t >> 5) & 3;
    int ns = t >> 7;
    const float* zg = zG + ns*ZZ;
    const float* m  = M + k*ZZ*ZZ;
    float acc = 0.0f;
#pragma unroll
    for (int i = 0; i < ZZ; ++i) acc += zg[i] * m[i*ZZ + j];
    qb[t] = f2b(acc);
}

// deg count
__global__ void k_deg(const int* __restrict__ dst, int* __restrict__ deg_i) {
    int e = blockIdx.x * blockDim.x + threadIdx.x;
    if (e < NE) atomicAdd(deg_i + dst[e], 1);
}

// C2: exclusive scan of deg_i -> offsets[0..NN], cursor copy (1 block, Hillis-Steele)
__global__ void k_scan(const int* __restrict__ deg_i, int* __restrict__ offsets,
                       int* __restrict__ cursor) {
    __shared__ int buf0[1024], buf1[1024];
    int tidx = threadIdx.x;
    const int CH = (NN + 1023) / 1024;   // 10
    int b0 = tidx * CH;
    int sum = 0;
    for (int i = 0; i < CH; ++i) { int idx = b0 + i; if (idx < NN) sum += deg_i[idx]; }
    buf0[tidx] = sum;
    __syncthreads();
    int* s = buf0; int* d = buf1;
    for (int off = 1; off < 1024; off <<= 1) {
        d[tidx] = s[tidx] + (tidx >= off ? s[tidx - off] : 0);
        __syncthreads();
        int* tmp = s; s = d; d = tmp;
    }
    int run = s[tidx] - sum;   // exclusive prefix of this thread's chunk
    for (int i = 0; i < CH; ++i) {
        int idx = b0 + i;
        if (idx < NN) { offsets[idx] = run; cursor[idx] = run; run += deg_i[idx]; }
    }
    if (tidx == 0) offsets[NN] = NE;
}

// C3: scatter src/dst node ids into dst-sorted position order
__global__ void k_scatter(const int* __restrict__ src, const int* __restrict__ dst,
                          int* __restrict__ cursor, int* __restrict__ src_by_pos,
                          int* __restrict__ dst_by_pos) {
    int e = blockIdx.x * blockDim.x + threadIdx.x;
    if (e >= NE) return;
    int sn = src[e], dn = dst[e];
    int pos = atomicAdd(cursor + dn, 1);
    src_by_pos[pos] = sn;
    dst_by_pos[pos] = dn;
}

// A2 v3: CSR-order edge scores from bf16 q/zG; e_csr[idx,s,k] contiguous
__global__ __launch_bounds__(256) void k_edge_e(
    const unsigned short* __restrict__ qb, const unsigned short* __restrict__ zGb,
    const int* __restrict__ src_by_pos, const int* __restrict__ dst_by_pos,
    float* __restrict__ e_csr) {
    int t = blockIdx.x * blockDim.x + threadIdx.x;
    if (t >= NE*SS) return;
    int s = t & 1;
    int idx = t >> 1;
    int sn = src_by_pos[idx], dn = dst_by_pos[idx];
    const unsigned* zp = (const unsigned*)(zGb + (dn*SS + s)*ZZ);
    float zf[32];
#pragma unroll
    for (int j = 0; j < 16; ++j) {
        unsigned u = zp[j];
        zf[2*j]   = __uint_as_float(u << 16);
        zf[2*j+1] = __uint_as_float(u & 0xffff0000u);
    }
    const unsigned* qp = (const unsigned*)(qb + (sn*SS + s)*KK*ZZ);
    float ev[4];
#pragma unroll
    for (int k = 0; k < 4; ++k) {
        float a = 0.f;
#pragma unroll
        for (int j = 0; j < 16; ++j) {
            unsigned u = qp[k*16 + j];
            a += __uint_as_float(u << 16) * zf[2*j]
               + __uint_as_float(u & 0xffff0000u) * zf[2*j+1];
        }
        ev[k] = a > 0.f ? a : 0.01f*a;
    }
    *(float4*)(e_csr + t*4) = *(float4*)ev;
}

// A3: per-(n,s) softmax stats via CSR; inv_den has 1/deg folded in
__global__ __launch_bounds__(64) void k_softmax_csr(
    const float* __restrict__ e_csr, const int* __restrict__ offsets,
    float* __restrict__ m_arr, float* __restrict__ inv_den) {
    int item = blockIdx.x;
    int n = item >> 1, s = item & 1;
    int l = threadIdx.x;
    int i = l >> 2, k = l & 3;
    int r0 = offsets[n], r1 = offsets[n+1];
    float mx = -1e30f;
    for (int idx = r0 + i; idx < r1; idx += 16)
        mx = fmaxf(mx, e_csr[(idx*2 + s)*4 + k]);
#pragma unroll
    for (int off = 4; off < 64; off <<= 1) mx = fmaxf(mx, __shfl_xor(mx, off));
    float sum = 0.f;
    for (int idx = r0 + i; idx < r1; idx += 16)
        sum += __expf(e_csr[(idx*2 + s)*4 + k] - mx);
#pragma unroll
    for (int off = 4; off < 64; off <<= 1) sum += __shfl_xor(sum, off);
    if (l < 4) {
        int deg = r1 - r0;
        float dd = (float)(deg > 1 ? deg : 1);
        m_arr[item*4 + l] = mx;
        inv_den[item*4 + l] = sum > 0.f ? 1.f/(sum*dd) : 0.f;
    }
}

// A4: alpha[idx,s,k] = exp(e - m[dst]) * inv_den (deg folded)
__global__ void k_alpha(const float* __restrict__ e_csr, const int* __restrict__ dst_by_pos,
                        const float* __restrict__ m_arr, const float* __restrict__ inv_den,
                        float* __restrict__ alpha) {
    int t = blockIdx.x * blockDim.x + threadIdx.x;
    if (t >= NE*SS) return;
    int s = t & 1;
    int idx = t >> 1;
    int item = dst_by_pos[idx]*2 + s;
    float4 ev = *(const float4*)(e_csr + t*4);
    float4 m4 = *(const float4*)(m_arr + item*4);
    float4 d4 = *(const float4*)(inv_den + item*4);
    float4 w;
    w.x = __expf(ev.x - m4.x) * d4.x;
    w.y = __expf(ev.y - m4.y) * d4.y;
    w.z = __expf(ev.z - m4.z) * d4.z;
    w.w = __expf(ev.w - m4.w) * d4.w;
    *(float4*)(alpha + t*4) = w;
}

// W0: convert all step-phase constants to bf16 (weights + zA + zG)
__global__ void k_conv_all(const float* __restrict__ F2w1, const float* __restrict__ F2w2,
                           const float* __restrict__ F1w1, const float* __restrict__ F1w2,
                           const float* __restrict__ ow1, const float* __restrict__ ow2,
                           const float* __restrict__ zA, const float* __restrict__ zG,
                           unsigned short* __restrict__ W1b, unsigned short* __restrict__ W2b,
                           unsigned short* __restrict__ F1w1b, unsigned short* __restrict__ F1w2b,
                           unsigned short* __restrict__ ow1b, unsigned short* __restrict__ ow2b,
                           unsigned short* __restrict__ zAb, unsigned short* __restrict__ zGb) {
    int t = blockIdx.x * blockDim.x + threadIdx.x;
    if (t < NN*SS*ZZ) { zAb[t] = f2b(zA[t]); zGb[t] = f2b(zG[t]); }
    if (t < HH*2*HH)  W1b[t] = f2b(F2w1[t]);
    if (t < HH*HH)    { W2b[t] = f2b(F2w2[t]); F1w2b[t] = f2b(F1w2[t]); }
    if (t < HH*KK*HH) F1w1b[t] = f2b(F1w1[t]);
    if (t < HH*(HH+ZZ)) ow1b[t] = f2b(ow1[t]);
    if (t < 4*HH)     ow2b[t] = f2b(ow2[t]);
}

// B0: xt[n,s,i] = inputs[n, 0, i]
__global__ void k_xt0(const float* __restrict__ inputs, float* __restrict__ xt) {
    int t = blockIdx.x * blockDim.x + threadIdx.x;
    if (t >= NN*SS*NIN) return;
    int i = t & 3;
    int n = t >> 3;
    xt[t] = inputs[n*(TT*NIN) + i];
}

// B1: xt_enc (bf16) = xt @ xenc_w.T + b
__global__ void k_xenc(const float* __restrict__ xt, const float* __restrict__ w,
                       const float* __restrict__ b, unsigned short* __restrict__ xtb) {
    int t = blockIdx.x * blockDim.x + threadIdx.x;
    if (t >= NN*SS*HH) return;
    int h  = t & 63;
    int ns = t >> 6;
    const float* x = xt + ns*NIN;
    float acc = b[h];
#pragma unroll
    for (int i = 0; i < NIN; ++i) acc += x[i] * w[h*NIN + i];
    xtb[t] = f2b(acc);
}

// B2: edge MLP MFMA GEMM, barrier-free direct-gather, persistent + 2-stage pipeline.
__global__ __launch_bounds__(256) void k_edge_mfma(
    const unsigned short* __restrict__ xtb, const unsigned short* __restrict__ W1b,
    const unsigned short* __restrict__ W2b, const int* __restrict__ src_by_pos,
    const int* __restrict__ dst_by_pos, unsigned short* __restrict__ dA)
{
    __shared__ unsigned short hid_s[4][16*72];   // per-wave only; no block barrier
    const int NT = NE*SS/64;   // 5000 tiles
    int tid = threadIdx.x;
    int w = tid >> 6, l = tid & 63, l15 = l & 15, qq = l >> 4;
    int s = l15 & 1;
    int eslot = w*8 + (l15 >> 1);

    bf16x8 b1[4][4], b2[2][4];
#pragma unroll
    for (int nb = 0; nb < 4; ++nb) {
        int n = nb*16 + l15;
#pragma unroll
        for (int kb = 0; kb < 4; ++kb)
            b1[kb][nb] = *(const bf16x8*)(W1b + n*128 + kb*32 + qq*8);
#pragma unroll
        for (int kb = 0; kb < 2; ++kb)
            b2[kb][nb] = *(const bf16x8*)(W2b + n*64 + kb*32 + qq*8);
    }

    int G = gridDim.x;
    int t = blockIdx.x;

    int p0 = t*32 + eslot;
    int sn0 = src_by_pos[p0], dn0 = dst_by_pos[p0];
    const unsigned short* ps = xtb + (sn0*SS + s)*HH + qq*8;
    const unsigned short* pd = xtb + (dn0*SS + s)*HH + qq*8;
    bf16x8 a0 = *(const bf16x8*)(ps);
    bf16x8 a1 = *(const bf16x8*)(ps + 32);
    bf16x8 a2 = *(const bf16x8*)(pd);
    bf16x8 a3 = *(const bf16x8*)(pd + 32);
    int t1 = t + G;
    int tc1 = t1 < NT ? t1 : 0;
    int sn1 = src_by_pos[tc1*32 + eslot], dn1 = dst_by_pos[tc1*32 + eslot];

    for (; t < NT; t += G) {
        const unsigned short* ps1 = xtb + (sn1*SS + s)*HH + qq*8;
        const unsigned short* pd1 = xtb + (dn1*SS + s)*HH + qq*8;
        bf16x8 n0 = *(const bf16x8*)(ps1);
        bf16x8 n1 = *(const bf16x8*)(ps1 + 32);
        bf16x8 n2 = *(const bf16x8*)(pd1);
        bf16x8 n3 = *(const bf16x8*)(pd1 + 32);
        int t2 = t + 2*G;
        int tc2 = t2 < NT ? t2 : 0;
        int sn2 = src_by_pos[tc2*32 + eslot], dn2 = dst_by_pos[tc2*32 + eslot];

        f32x4 acc[4];
#pragma unroll
        for (int nb = 0; nb < 4; ++nb) acc[nb] = (f32x4)(0.0f);
#pragma unroll
        for (int nb = 0; nb < 4; ++nb) {
            acc[nb] = __builtin_amdgcn_mfma_f32_16x16x32_bf16(a0, b1[0][nb], acc[nb], 0, 0, 0);
            acc[nb] = __builtin_amdgcn_mfma_f32_16x16x32_bf16(a1, b1[1][nb], acc[nb], 0, 0, 0);
            acc[nb] = __builtin_amdgcn_mfma_f32_16x16x32_bf16(a2, b1[2][nb], acc[nb], 0, 0, 0);
            acc[nb] = __builtin_amdgcn_mfma_f32_16x16x32_bf16(a3, b1[3][nb], acc[nb], 0, 0, 0);
        }
        unsigned short* hw = hid_s[w];
#pragma unroll
        for (int nb = 0; nb < 4; ++nb)
#pragma unroll
            for (int r = 0; r < 4; ++r) {
                float v = acc[nb][r];
                hw[(qq*4 + r)*72 + nb*16 + l15] = f2b(v > 0.0f ? v : 0.0f);
            }
        f32x4 acc2[4];
#pragma unroll
        for (int nb = 0; nb < 4; ++nb) acc2[nb] = (f32x4)(0.0f);
        const unsigned short* a2row = hw + l15*72 + qq*8;
#pragma unroll
        for (int kb = 0; kb < 2; ++kb) {
            bf16x8 af = *(const bf16x8*)(a2row + kb*32);
#pragma unroll
            for (int nb = 0; nb < 4; ++nb)
                acc2[nb] = __builtin_amdgcn_mfma_f32_16x16x32_bf16(af, b2[kb][nb], acc2[nb], 0, 0, 0);
        }
        unsigned short* drow = dA + (t*64 + w*16)*64;
#pragma unroll
        for (int nb = 0; nb < 4; ++nb)
#pragma unroll
            for (int r = 0; r < 4; ++r)
                drow[(qq*4 + r)*64 + nb*16 + l15] = f2b(acc2[nb][r]);

        a0 = n0; a1 = n1; a2 = n2; a3 = n3;
        sn1 = sn2; dn1 = dn2;
    }
}

// B2b: aggregation per (n,s): pure stream of alpha (broadcast) + dA rows
__global__ __launch_bounds__(64) void k_agg(
    const unsigned short* __restrict__ dA, const int* __restrict__ offsets,
    const float* __restrict__ alpha, unsigned short* __restrict__ res_b)
{
    int item = blockIdx.x;
    int n = item >> 1, s = item & 1;
    int h = threadIdx.x;
    int r0 = offsets[n], r1 = offsets[n+1];
    float a0 = 0.f, a1 = 0.f, a2 = 0.f, a3 = 0.f;
    for (int idx = r0; idx < r1; ++idx) {
        int row = idx*2 + s;
        const float4 w4 = *(const float4*)(alpha + row*4);
        unsigned short uv = dA[row*64 + h];
        float v = __uint_as_float(((unsigned)uv) << 16);
        a0 += w4.x*v; a1 += w4.y*v; a2 += w4.z*v; a3 += w4.w*v;
    }
    res_b[item*256 +       h] = f2b(a0);
    res_b[item*256 + 64  + h] = f2b(a1);
    res_b[item*256 + 128 + h] = f2b(a2);
    res_b[item*256 + 192 + h] = f2b(a3);
}

// B3: node update as chained bf16 MFMA GEMMs. 4 waves/block, 16 items/wave.
__global__ __launch_bounds__(256) void k_node_mfma(
    const unsigned short* __restrict__ res_b, const unsigned short* __restrict__ zAb,
    const unsigned short* __restrict__ F1w1b, const unsigned short* __restrict__ F1w2b,
    const unsigned short* __restrict__ ow1b, const unsigned short* __restrict__ ow2b,
    const float* __restrict__ ob1, const float* __restrict__ ob2,
    float* __restrict__ xt, float* __restrict__ out, int tstep)
{
    __shared__ unsigned short w1s[64*264];
    __shared__ unsigned short hid_s[4][16*72];
    __shared__ unsigned short hcat_s[4][16*104];
    int tid = threadIdx.x;
    int w = tid >> 6, l = tid & 63, l15 = l & 15, qq = l >> 4;

    for (int i = tid; i < 64*32; i += 256) {
        int r = i >> 5, c = i & 31;
        *(uint4*)(w1s + r*264 + c*8) = *(const uint4*)(F1w1b + r*256 + c*8);
    }
    bf16x8 b2f[2][4], o1f[3][4], bo2[2];
#pragma unroll
    for (int nb = 0; nb < 4; ++nb) {
        int n = nb*16 + l15;
#pragma unroll
        for (int kb = 0; kb < 2; ++kb)
            b2f[kb][nb] = *(const bf16x8*)(F1w2b + n*64 + kb*32 + qq*8);
#pragma unroll
        for (int kb = 0; kb < 3; ++kb)
            o1f[kb][nb] = *(const bf16x8*)(ow1b + n*96 + kb*32 + qq*8);
    }
#pragma unroll
    for (int kb = 0; kb < 2; ++kb) {
        if (l15 < 4) bo2[kb] = *(const bf16x8*)(ow2b + l15*64 + kb*32 + qq*8);
        else {
            bf16x8 z;
#pragma unroll
            for (int j = 0; j < 8; ++j) z[j] = 0;
            bo2[kb] = z;
        }
    }
    float b1v[4];
#pragma unroll
    for (int nb = 0; nb < 4; ++nb) b1v[nb] = ob1[nb*16 + l15];
    float b2v = (l15 < 4) ? ob2[l15] : 0.0f;
    __syncthreads();

    int itemBase = blockIdx.x*64 + w*16;
    if (itemBase >= NN*SS) return;

    *(uint4*)(&hcat_s[w][l15*104 + 64 + qq*8]) =
        *(const uint4*)(zAb + (itemBase + l15)*ZZ + qq*8);

    f32x4 acc[4];
#pragma unroll
    for (int nb = 0; nb < 4; ++nb) acc[nb] = (f32x4)(0.0f);
#pragma unroll
    for (int kb = 0; kb < 8; ++kb) {
        bf16x8 af = *(const bf16x8*)(res_b + (itemBase + l15)*256 + kb*32 + qq*8);
#pragma unroll
        for (int nb = 0; nb < 4; ++nb) {
            bf16x8 bf = *(const bf16x8*)(w1s + (nb*16 + l15)*264 + kb*32 + qq*8);
            acc[nb] = __builtin_amdgcn_mfma_f32_16x16x32_bf16(af, bf, acc[nb], 0, 0, 0);
        }
    }
#pragma unroll
    for (int nb = 0; nb < 4; ++nb)
#pragma unroll
        for (int r = 0; r < 4; ++r) {
            float v = acc[nb][r];
            hid_s[w][(qq*4 + r)*72 + nb*16 + l15] = f2b(v > 0.0f ? v : 0.0f);
        }

    f32x4 acc2[4];
#pragma unroll
    for (int nb = 0; nb < 4; ++nb) acc2[nb] = (f32x4)(0.0f);
#pragma unroll
    for (int kb = 0; kb < 2; ++kb) {
        bf16x8 af = *(const bf16x8*)(&hid_s[w][l15*72 + kb*32 + qq*8]);
#pragma unroll
        for (int nb = 0; nb < 4; ++nb)
            acc2[nb] = __builtin_amdgcn_mfma_f32_16x16x32_bf16(af, b2f[kb][nb], acc2[nb], 0, 0, 0);
    }
#pragma unroll
    for (int nb = 0; nb < 4; ++nb)
#pragma unroll
        for (int r = 0; r < 4; ++r)
            hcat_s[w][(qq*4 + r)*104 + nb*16 + l15] = f2b(acc2[nb][r]);

    f32x4 acc3[4];
#pragma unroll
    for (int nb = 0; nb < 4; ++nb) acc3[nb] = (f32x4)(0.0f);
#pragma unroll
    for (int kb = 0; kb < 3; ++kb) {
        bf16x8 af = *(const bf16x8*)(&hcat_s[w][l15*104 + kb*32 + qq*8]);
#pragma unroll
        for (int nb = 0; nb < 4; ++nb)
            acc3[nb] = __builtin_amdgcn_mfma_f32_16x16x32_bf16(af, o1f[kb][nb], acc3[nb], 0, 0, 0);
    }
#pragma unroll
    for (int nb = 0; nb < 4; ++nb)
#pragma unroll
        for (int r = 0; r < 4; ++r) {
            float v = acc3[nb][r] + b1v[nb];
            hid_s[w][(qq*4 + r)*72 + nb*16 + l15] = f2b(v > 0.0f ? v : 0.0f);
        }

    f32x4 acc4 = (f32x4)(0.0f);
#pragma unroll
    for (int kb = 0; kb < 2; ++kb) {
        bf16x8 af = *(const bf16x8*)(&hid_s[w][l15*72 + kb*32 + qq*8]);
        acc4 = __builtin_amdgcn_mfma_f32_16x16x32_bf16(af, bo2[kb], acc4, 0, 0, 0);
    }
    if (l15 < 4) {
#pragma unroll
        for (int r = 0; r < 4; ++r) {
            int item = itemBase + qq*4 + r;
            float nx = xt[item*4 + l15] + acc4[r] + b2v;
            xt[item*4 + l15] = nx;
            int n = item >> 1, s = item & 1;
            out[((n*TT + tstep)*SS + s)*4 + l15] = nx;
        }
    }
}

extern "C" void kernel_launch(void* const* d_in, const int* in_sizes, int n_in,
                              void* d_out, int out_size, void* d_ws, size_t ws_size,
                              hipStream_t stream) {
    const float* inputs = (const float*)d_in[0];
    const float* zA     = (const float*)d_in[1];
    const float* zG     = (const float*)d_in[2];
    const int*   src    = (const int*)d_in[3];
    const int*   dst    = (const int*)d_in[4];
    const float* Ws     = (const float*)d_in[5];
    const float* Wd     = (const float*)d_in[6];
    const float* F2w1   = (const float*)d_in[7];
    const float* F2w2   = (const float*)d_in[8];
    const float* F1w1   = (const float*)d_in[9];
    const float* F1w2   = (const float*)d_in[10];
    const float* xw     = (const float*)d_in[11];
    const float* xb     = (const float*)d_in[12];
    const float* ow1    = (const float*)d_in[13];
    const float* ob1    = (const float*)d_in[14];
    const float* ow2    = (const float*)d_in[15];
    const float* ob2    = (const float*)d_in[16];
    float* out = (float*)d_out;

    // ---- workspace carve (units: floats) ----
    float*          base        = (float*)d_ws;
    float*          M           = base;                              // 4,096
    float*          e_csr       = base + 4096;                       // 1,280,000
    float*          alpha       = base + 1284096;                    // 1,280,000
    float*          m_arr       = base + 2564096;                    // 80,000
    float*          inv_den     = base + 2644096;                    // 80,000
    int*            deg_i       = (int*)(base + 2724096);            // 10,000 (zeroed)
    int*            offsets     = (int*)(base + 2734096);            // 10,016
    int*            cursor      = (int*)(base + 2744112);            // 10,000
    int*            src_by_pos  = (int*)(base + 2754112);            // 160,000
    int*            dst_by_pos  = (int*)(base + 2914112);            // 160,000
    float*          xt          = base + 3074112;                    // 80,000
    unsigned short* xtb         = (unsigned short*)(base + 3154112); // 1,280,000 ush
    unsigned short* W1b         = (unsigned short*)(base + 3794112); // 8,192 ush
    unsigned short* W2b         = (unsigned short*)(base + 3798208); // 4,096 ush
    unsigned short* F1w1b       = (unsigned short*)(base + 3800256); // 16,384 ush
    unsigned short* F1w2b       = (unsigned short*)(base + 3808448); // 4,096 ush
    unsigned short* ow1b        = (unsigned short*)(base + 3810496); // 6,144 ush
    unsigned short* ow2b        = (unsigned short*)(base + 3813568); // 256 ush
    unsigned short* zAb         = (unsigned short*)(base + 3813696); // 640,000 ush
    unsigned short* zGb         = (unsigned short*)(base + 4133696); // 640,000 ush
    unsigned short* res_b       = (unsigned short*)(base + 4453696); // 5,120,000 ush
    // phase union @ 7,013,696: qb (2.56M ush, attention) / dA (20.48M ush, steps)
    unsigned short* qb          = (unsigned short*)(base + 7013696);
    unsigned short* dA          = (unsigned short*)(base + 7013696);
    // total 17,253,696 floats = 69.0 MB

    hipMemsetAsync(deg_i, 0, 10000u * 4u, stream);

    // ---- attention phase (once) ----
    k_attnM<<<KK*ZZ, ZZ, 0, stream>>>(Ws, Wd, M);
    k_q<<<(NN*SS*KK*ZZ + 255)/256, 256, 0, stream>>>(zG, M, qb);
    k_conv_all<<<(NN*SS*ZZ + 255)/256, 256, 0, stream>>>(F2w1, F2w2, F1w1, F1w2, ow1, ow2,
                                                         zA, zG, W1b, W2b, F1w1b, F1w2b,
                                                         ow1b, ow2b, zAb, zGb);
    k_deg<<<(NE + 255)/256, 256, 0, stream>>>(dst, deg_i);
    k_scan<<<1, 1024, 0, stream>>>(deg_i, offsets, cursor);
    k_scatter<<<(NE + 255)/256, 256, 0, stream>>>(src, dst, cursor, src_by_pos, dst_by_pos);
    k_edge_e<<<(NE*SS + 255)/256, 256, 0, stream>>>(qb, zGb, src_by_pos, dst_by_pos, e_csr);
    k_softmax_csr<<<NN*SS, 64, 0, stream>>>(e_csr, offsets, m_arr, inv_den);
    k_alpha<<<(NE*SS + 255)/256, 256, 0, stream>>>(e_csr, dst_by_pos, m_arr, inv_den, alpha);

    // ---- time stepping ----
    k_xt0<<<(NN*SS*NIN + 255)/256, 256, 0, stream>>>(inputs, xt);
    for (int t = 0; t < 2; ++t) {
        k_xenc<<<(NN*SS*HH + 255)/256, 256, 0, stream>>>(xt, xw, xb, xtb);
        k_edge_mfma<<<1024, 256, 0, stream>>>(xtb, W1b, W2b, src_by_pos, dst_by_pos, dA);
        k_agg<<<NN*SS, 64, 0, stream>>>(dA, offsets, alpha, res_b);
        k_node_mfma<<<(NN*SS + 63)/64, 256, 0, stream>>>(res_b, zAb, F1w1b, F1w2b,
                                                         ow1b, ow2b, ob1, ob2, xt, out, t);
    }
}